// Round 8
// baseline (198.835 us; speedup 1.0000x reference)
//
#include <hip/hip_runtime.h>

#define NN   32768
#define HD   128
#define EE   524288
#define GG   256
#define EPG  2048
#define CCd  16
#define LLd  3

typedef short short8 __attribute__((ext_vector_type(8)));   // 8 bf16 = 4 VGPRs
typedef float f32x4 __attribute__((ext_vector_type(4)));

__device__ __forceinline__ unsigned short f2bf(float f) {
  unsigned u = __builtin_bit_cast(unsigned, f);
  return (unsigned short)((u + 0x7FFFu + ((u >> 16) & 1u)) >> 16);  // RNE
}
__device__ __forceinline__ unsigned bfpack(float a, float b) {
  return (unsigned)f2bf(a) | ((unsigned)f2bf(b) << 16);
}

// hTs layout: [f][t] bf16, stride 128 (no pad), 16-B chunks XOR-swizzled:
//   phys = (c&8) | ((c ^ f ^ (f>>3)) & 7),  c = t>>3
__device__ __forceinline__ int hchunk(int f, int c) {
  return f * 128 + (((c & 8) | ((c ^ f ^ (f >> 3)) & 7)) << 3);
}
__device__ __forceinline__ int hidx(int f, int t) {
  return hchunk(f, t >> 3) + (t & 7);
}

// ---------------- convert weights to bf16 + reg_loss accumulate ----------------
__global__ __launch_bounds__(256) void convert_w_kernel(const float* __restrict__ Wn, const float* __restrict__ Wo,
                                                        const float* __restrict__ Wr, const float* __restrict__ bo,
                                                        unsigned* __restrict__ Wnb, unsigned* __restrict__ Wob,
                                                        unsigned* __restrict__ Wrb, float* __restrict__ wsreg) {
  int i = blockIdx.x * 256 + threadIdx.x;   // 48 blocks; 4 floats per array per thread
  float4 a = *(const float4*)(Wn + (size_t)i * 4);
  float4 b = *(const float4*)(Wo + (size_t)i * 4);
  float4 c = *(const float4*)(Wr + (size_t)i * 4);
  *(uint2*)(Wnb + (size_t)i * 2) = make_uint2(bfpack(a.x, a.y), bfpack(a.z, a.w));
  *(uint2*)(Wob + (size_t)i * 2) = make_uint2(bfpack(b.x, b.y), bfpack(b.z, b.w));
  *(uint2*)(Wrb + (size_t)i * 2) = make_uint2(bfpack(c.x, c.y), bfpack(c.z, c.w));
  float s = fabsf(b.x) + fabsf(b.y) + fabsf(b.z) + fabsf(b.w);
  if (blockIdx.x == 0 && threadIdx.x < 96) {       // 384 bo elements
    float4 d = *(const float4*)(bo + threadIdx.x * 4);
    s += fabsf(d.x) + fabsf(d.y) + fabsf(d.z) + fabsf(d.w);
  }
#pragma unroll
  for (int mk = 1; mk < 64; mk <<= 1) s += __shfl_xor(s, mk, 64);
  if ((threadIdx.x & 63) == 0) atomicAdd(wsreg, s);
}

// ---------------- fully fused per-graph network ----------------
// grid 256 (1 block/graph), 512 threads (8 waves; wave w owns node rows [16w,16w+16)).
// LAUNCH BOUNDS NOTE: (512, 1) NOT (512, 2). The ",2" caps VGPR at 128 (16 waves/CU
// per m69) and forced accumulator spills in r1/r4/r7 (WRITE_SIZE 80MB signature).
// Grid == 256 == 1 block/CU, so 2-blocks/CU residency is unreachable anyway.
// Structure (correctness-proven r7): (a) M B-frags in 32 persistent VGPRs;
// (b) THREE resident W slots (Wlds=Wn, Mlds-lo=Wo, Mlds-hi=Wr) -> 2 barriers/layer,
// W loads issue a phase early (T14); (c) edge loads prefetched at entry.
// MFMA operands never read directly from global (r1/r4 lesson).
__global__ __launch_bounds__(512, 1) void fused_kernel(
    const float* __restrict__ x,
    const int* __restrict__ esrc, const int* __restrict__ etgt, const int* __restrict__ emask,
    const unsigned short* __restrict__ Wnb, const unsigned short* __restrict__ Wob,
    const unsigned short* __restrict__ Wrb,
    const float* __restrict__ bn, const float* __restrict__ bo,
    const float* __restrict__ lng, const float* __restrict__ lnb,
    const float* __restrict__ s,
    const float* __restrict__ flng, const float* __restrict__ flnb,
    const float* __restrict__ linw, const float* __restrict__ bias,
    float* __restrict__ out, float* __restrict__ l1g) {
  __shared__ __align__(16) unsigned short hTs[128 * 128];  // 32.0 KB  h^T, XOR-swizzled
  __shared__ __align__(16) unsigned short sTs[16 * 136];   //  4.3 KB  s^T [c][t]
  __shared__ __align__(16) unsigned Mlds[2 * 128 * 64];    // 64.0 KB  counts -> W slots B,C; pool scratch
  __shared__ __align__(16) unsigned Wlds[128 * 64];        // 32.0 KB  W slot A
  __shared__ float finS[128], foutS[128];
  __shared__ float colsumS[CCd], xcs[CCd], axcs[CCd], msk[CCd];

  const int g = blockIdx.x;
  const int tid = threadIdx.x;
  const int wave = tid >> 6;
  const int lane = tid & 63;
  const int m = lane & 15;
  const int q = lane >> 4;
  const int t0 = wave << 4;

  unsigned* const slotB = Mlds;          // Wo resident
  unsigned* const slotC = Mlds + 8192;   // Wr resident

  // ---- W prefetch machinery (bf16 global -> regs -> swizzled LDS slot) ----
  const int wr = tid >> 2, wq = tid & 3, wsw = wr & 7;
  const int wbase = wr * 16 + wq * 4;
  auto w_issue = [&](const unsigned short* Wg, uint4& a, uint4& b, uint4& c, uint4& d) {
    const uint4* wp = (const uint4*)Wg;
    a = wp[wbase + 0]; b = wp[wbase + 1]; c = wp[wbase + 2]; d = wp[wbase + 3];
  };
  auto w_slot = [&](unsigned* slot, const uint4& a, const uint4& b, const uint4& c, const uint4& d) {
    *(uint4*)&slot[wr * 64 + (((wq * 4 + 0) ^ wsw) << 2)] = a;
    *(uint4*)&slot[wr * 64 + (((wq * 4 + 1) ^ wsw) << 2)] = b;
    *(uint4*)&slot[wr * 64 + (((wq * 4 + 2) ^ wsw) << 2)] = c;
    *(uint4*)&slot[wr * 64 + (((wq * 4 + 3) ^ wsw) << 2)] = d;
  };
  // B-frag read from a W slot (same swizzle as w_slot; row&7 == m&7)
  auto wfrag = [&](const unsigned* slot, int ct, int ksg) -> short8 {
    return *(const short8*)&slot[(ct * 16 + m) * 64 + (((ksg * 4 + q) ^ (m & 7)) << 2)];
  };

  // ---- entry: issue W(L=0) x3 and edge loads (latency hides under phases 0-2) ----
  uint4 p10, p11, p12, p13, p20, p21, p22, p23, p30, p31, p32, p33;
  w_issue(Wnb, p10, p11, p12, p13);
  w_issue(Wob, p20, p21, p22, p23);
  w_issue(Wrb, p30, p31, p32, p33);
  int et[4], es[4], em[4];
  {
    const int e0 = g * EPG;
#pragma unroll
    for (int i = 0; i < 4; ++i) {
      int e = e0 + i * 512 + tid;
      et[i] = etgt[e]; es[i] = esrc[e]; em[i] = emask[e];
    }
  }

  // ---- phase 0: zero counts + stage x->hTs (swizzled), s->sTs, colsum ----
  {
    uint4* cz = (uint4*)Mlds;   // 4096 uint4
#pragma unroll
    for (int i = 0; i < 8; ++i) cz[i * 512 + tid] = make_uint4(0u, 0u, 0u, 0u);

    const float4* xg = (const float4*)(x + (size_t)g * 16384);
#pragma unroll
    for (int i = 0; i < 8; ++i) {
      int flat = i * 512 + tid;           // 4096 float4s, fully coalesced
      int t = flat >> 5, f0 = (flat & 31) << 2;
      float4 v = xg[flat];
      hTs[hidx(f0 + 0, t)] = f2bf(v.x);
      hTs[hidx(f0 + 1, t)] = f2bf(v.y);
      hTs[hidx(f0 + 2, t)] = f2bf(v.z);
      hTs[hidx(f0 + 3, t)] = f2bf(v.w);
    }
    {
      int t = tid >> 2, c0 = (tid & 3) << 2;
      float4 v = *(const float4*)(s + (size_t)g * 2048 + t * 16 + c0);
      sTs[(c0 + 0) * 136 + t] = f2bf(v.x);
      sTs[(c0 + 1) * 136 + t] = f2bf(v.y);
      sTs[(c0 + 2) * 136 + t] = f2bf(v.z);
      sTs[(c0 + 3) * 136 + t] = f2bf(v.w);
    }
    if (tid < 64) {            // colsum: 4 lanes per column
      int c = tid & 15, qq = tid >> 4;
      float cs = 0.f;
      for (int tt = qq; tt < 128; tt += 4) cs += s[(size_t)g * 2048 + tt * 16 + c];
      cs += __shfl_xor(cs, 16); cs += __shfl_xor(cs, 32);
      if (qq == 0) colsumS[c] = cs;
    }
  }
  __syncthreads();

  // ---- phase 1: edge binning from prefetched regs, swizzled quads ----
  {
#pragma unroll
    for (int i = 0; i < 4; ++i) {
      int t = et[i] & 127;
      int sl = es[i] & 127;
      int dir = (em[i] != 0) ? 0 : 1;
      atomicAdd(&Mlds[dir * 8192 + t * 64 + (((sl >> 3) ^ (t & 7)) << 2) + ((sl >> 1) & 3)],
                1u << ((sl & 1) * 16));
    }
  }
  __syncthreads();

  // ---- phase 2: degrees + extract own M B-frags to registers (no LDS writes) ----
  short8 mfr[2][4];   // [dir][ksg] : M[t0+m][k=ksg*32+q*8+j] * inv, bf16
  {
    const int t = t0 + m;
    const int mm = m & 7;
    unsigned nin = 0, nout = 0;
#pragma unroll
    for (int k4 = 0; k4 < 4; ++k4) {
      int sl = (((q * 4 + k4) ^ mm) & 15) << 2;
      uint4 a = *(const uint4*)&Mlds[t * 64 + sl];
      uint4 b = *(const uint4*)&Mlds[8192 + t * 64 + sl];
      nin  += (a.x & 0xffffu) + (a.x >> 16) + (a.y & 0xffffu) + (a.y >> 16)
            + (a.z & 0xffffu) + (a.z >> 16) + (a.w & 0xffffu) + (a.w >> 16);
      nout += (b.x & 0xffffu) + (b.x >> 16) + (b.y & 0xffffu) + (b.y >> 16)
            + (b.z & 0xffffu) + (b.z >> 16) + (b.w & 0xffffu) + (b.w >> 16);
    }
    nin  += __shfl_xor((int)nin, 16);  nin  += __shfl_xor((int)nin, 32);
    nout += __shfl_xor((int)nout, 16); nout += __shfl_xor((int)nout, 32);
    unsigned dg = nin + nout;
    float inv = 1.0f / (float)(dg > 0 ? dg : 1);
    if (q == 0) { finS[t] = (float)nin * inv; foutS[t] = (float)nout * inv; }
#pragma unroll
    for (int d = 0; d < 2; ++d)
#pragma unroll
      for (int ksg = 0; ksg < 4; ++ksg) {
        int sl = (((ksg * 4 + q) ^ mm) & 15) << 2;   // logical chunk ksg*4+q
        uint4 v = *(const uint4*)&Mlds[d * 8192 + t * 64 + sl];
        uint4 o;
        o.x = bfpack((float)(v.x & 0xffffu) * inv, (float)(v.x >> 16) * inv);
        o.y = bfpack((float)(v.y & 0xffffu) * inv, (float)(v.y >> 16) * inv);
        o.z = bfpack((float)(v.z & 0xffffu) * inv, (float)(v.z >> 16) * inv);
        o.w = bfpack((float)(v.w & 0xffffu) * inv, (float)(v.w >> 16) * inv);
        mfr[d][ksg] = __builtin_bit_cast(short8, o);
      }
  }
  __syncthreads();   // all count reads done -> Mlds reusable as W slots

  // ---- fill the three W slots (loads long since arrived) ----
  w_slot(Wlds,  p10, p11, p12, p13);   // Wn[0]
  w_slot(slotB, p20, p21, p22, p23);   // Wo[0]
  w_slot(slotC, p30, p31, p32, p33);   // Wr[0]
  __syncthreads();

  // ---- layers: 2 barriers each ----
  for (int L = 0; L < LLd; ++L) {
    const bool more = (L < LLd - 1);
    if (more) {          // next-layer Wn/Wo in flight across the whole layer
      w_issue(Wnb + (L + 1) * 16384, p10, p11, p12, p13);
      w_issue(Wob + (L + 1) * 16384, p20, p21, p22, p23);
    }
    f32x4 pre[8];
#pragma unroll
    for (int ct = 0; ct < 8; ++ct) pre[ct] = (f32x4){0.f, 0.f, 0.f, 0.f};
    f32x4 accT[8];

#pragma unroll
    for (int sg = 0; sg < 2; ++sg) {
      const unsigned* slot = (sg == 0) ? (const unsigned*)Wlds : (const unsigned*)slotB;
      // --- M phase: accT[ft] = (Agg^T)[f-tile][t-slice], B-frags from registers ---
#pragma unroll
      for (int ft = 0; ft < 8; ++ft) accT[ft] = (f32x4){0.f, 0.f, 0.f, 0.f};
#pragma unroll
      for (int hf = 0; hf < 2; ++hf)
#pragma unroll
        for (int ksl = 0; ksl < 2; ++ksl) {
          const int ksg = hf * 2 + ksl;
          short8 bfr = mfr[sg][ksg];
#pragma unroll
          for (int ft = 0; ft < 8; ++ft) {
            short8 afr = *(const short8*)&hTs[hchunk(ft * 16 + m, ksg * 4 + q)];
            accT[ft] = __builtin_amdgcn_mfma_f32_16x16x32_bf16(afr, bfr, accT[ft], 0, 0, 0);
          }
        }
      // --- main phase: pre += Agg * W^T (packed single-shfl transpose; B from slot) ---
#pragma unroll
      for (int hf = 0; hf < 2; ++hf)
#pragma unroll
        for (int ksl = 0; ksl < 2; ++ksl) {
          const int ksg = hf * 2 + ksl;
          f32x4 lo = accT[2 * ksg], hi = accT[2 * ksg + 1];
          unsigned pk[4];
#pragma unroll
          for (int r = 0; r < 4; ++r) pk[r] = bfpack(lo[r], hi[r]);
          short8 afr;
#pragma unroll
          for (int j = 0; j < 8; ++j) {
            int srcl = ((((q & 1) << 1) + (j >> 2)) << 4) + m;
            unsigned v = (unsigned)__shfl((int)pk[j & 3], srcl, 64);
            afr[j] = (short)(unsigned short)((q >> 1) ? (v >> 16) : (v & 0xffffu));
          }
#pragma unroll
          for (int ct = 0; ct < 8; ++ct) {
            short8 bfr = wfrag(slot, ct, ksg);
            pre[ct] = __builtin_amdgcn_mfma_f32_16x16x32_bf16(afr, bfr, pre[ct], 0, 0, 0);
          }
        }
    }
    // --- Wr segment: A-frags scalar-read from hTs, B from slot C ---
#pragma unroll
    for (int hf = 0; hf < 2; ++hf)
#pragma unroll
      for (int ksl = 0; ksl < 2; ++ksl) {
        const int ksg = hf * 2 + ksl;
        short8 afr;
#pragma unroll
        for (int j = 0; j < 8; ++j)
          afr[j] = (short)hTs[hidx(ksg * 32 + q * 8 + j, t0 + m)];
#pragma unroll
        for (int ct = 0; ct < 8; ++ct) {
          short8 bfr = wfrag(slotC, ct, ksg);
          pre[ct] = __builtin_amdgcn_mfma_f32_16x16x32_bf16(afr, bfr, pre[ct], 0, 0, 0);
        }
      }
    __syncthreads();   // bar1: all hTs + W-slot reads of this layer done
    if (more) {
      w_slot(Wlds,  p10, p11, p12, p13);   // Wn[L+1]
      w_slot(slotB, p20, p21, p22, p23);   // Wo[L+1]
      w_issue(Wrb + (L + 1) * 16384, p10, p11, p12, p13);  // Wr[L+1] hides under epilogue
    }
    // --- epilogue: bias mix + LN + ReLU -> hTs (own wave's t-columns: race-free) ---
    {
      float bnv[8], bov[8], gv[8], bv[8];
#pragma unroll
      for (int ct = 0; ct < 8; ++ct) {
        int c = L * 128 + ct * 16 + m;
        bnv[ct] = bn[c]; bov[ct] = bo[c]; gv[ct] = lng[c]; bv[ct] = lnb[c];
      }
#pragma unroll
      for (int r = 0; r < 4; ++r) {
        const int tl = q * 4 + r;
        const float fiv = finS[t0 + tl], fov = foutS[t0 + tl];
        float v[8];
        float sum = 0.f;
#pragma unroll
        for (int ct = 0; ct < 8; ++ct) {
          v[ct] = pre[ct][r] + fiv * bnv[ct] + fov * bov[ct];
          sum += v[ct];
        }
        sum += __shfl_xor(sum, 1); sum += __shfl_xor(sum, 2);
        sum += __shfl_xor(sum, 4); sum += __shfl_xor(sum, 8);
        const float mu = sum * (1.0f / 128.0f);
        float sq = 0.f;
#pragma unroll
        for (int ct = 0; ct < 8; ++ct) { float d = v[ct] - mu; sq += d * d; }
        sq += __shfl_xor(sq, 1); sq += __shfl_xor(sq, 2);
        sq += __shfl_xor(sq, 4); sq += __shfl_xor(sq, 8);
        const float rstd = rsqrtf(sq * (1.0f / 128.0f) + 1e-5f);
#pragma unroll
        for (int ct = 0; ct < 8; ++ct) {
          float o = fmaxf((v[ct] - mu) * rstd * gv[ct] + bv[ct], 0.0f);
          hTs[hidx(ct * 16 + m, t0 + tl)] = f2bf(o);
        }
      }
    }
    if (more) w_slot(slotC, p10, p11, p12, p13);   // Wr[L+1]
    __syncthreads();   // bar2: hTs + restocked slots visible
  }

  // ---- pool: pooled[c][fo] = sum_t s[t][c]*h[t][fo]; wave w does fo-tile w ----
  f32x4 pl = (f32x4){0.f, 0.f, 0.f, 0.f};
#pragma unroll
  for (int ks = 0; ks < 4; ++ks) {
    short8 a = *(const short8*)&sTs[m * 136 + ks * 32 + q * 8];
    short8 b = *(const short8*)&hTs[hchunk(wave * 16 + m, ks * 4 + q)];
    pl = __builtin_amdgcn_mfma_f32_16x16x32_bf16(a, b, pl, 0, 0, 0);
  }
  float* pooledS = (float*)Mlds;   // W slots dead after last layer
#pragma unroll
  for (int r = 0; r < 4; ++r) pooledS[(q * 4 + r) * 132 + wave * 16 + m] = pl[r];
  __syncthreads();

  // ---- final LN + lin + mask (threads 0..255) ----
  if (tid < 256) {
    const int c = tid >> 4;
    const int j0 = (tid & 15) << 3;
    float v[8];
#pragma unroll
    for (int jj = 0; jj < 8; ++jj) v[jj] = pooledS[c * 132 + j0 + jj];
    float sum = 0.f;
#pragma unroll
    for (int jj = 0; jj < 8; ++jj) sum += v[jj];
#pragma unroll
    for (int mk = 1; mk < 16; mk <<= 1) sum += __shfl_xor(sum, mk, 64);
    float mu = sum * (1.0f / 128.0f);
    float sq = 0.f;
#pragma unroll
    for (int jj = 0; jj < 8; ++jj) { float d = v[jj] - mu; sq += d * d; }
#pragma unroll
    for (int mk = 1; mk < 16; mk <<= 1) sq += __shfl_xor(sq, mk, 64);
    float rstd = rsqrtf(sq * (1.0f / 128.0f) + 1e-5f);
    float dot = 0.f;
#pragma unroll
    for (int jj = 0; jj < 8; ++jj) {
      float nv = (v[jj] - mu) * rstd * flng[j0 + jj] + flnb[j0 + jj];
      dot += nv * linw[j0 + jj];
    }
#pragma unroll
    for (int mk = 1; mk < 16; mk <<= 1) dot += __shfl_xor(dot, mk, 64);
    if ((tid & 15) == 0) {
      float cm = (colsumS[c] > 0.f) ? 1.0f : 0.0f;
      float xcv = dot * cm;
      out[257 + g * CCd + c] = xcv;
      xcs[c] = xcv; axcs[c] = fabsf(xcv); msk[c] = cm;
    }
  }
  __syncthreads();
  if (tid == 0) {
    float so = 0.f, sa = 0.f, sd = 0.f;
#pragma unroll
    for (int k = 0; k < CCd; ++k) { so += xcs[k]; sa += axcs[k]; sd += msk[k] + 1e-7f; }
    out[g] = so + bias[0];
    l1g[g] = sa / sd;
  }
}

// ---------------- combine: losses = 0.01*reg + 0.01*mean_g(l1g) ----------------
__global__ __launch_bounds__(256) void combine_kernel(const float* __restrict__ l1g, const float* __restrict__ wsreg,
                                                      float* __restrict__ outp) {
  const int tid = threadIdx.x;
  float s2 = l1g[tid];
#pragma unroll
  for (int mk = 1; mk < 64; mk <<= 1) s2 += __shfl_xor(s2, mk, 64);
  __shared__ float rs2[4];
  if ((tid & 63) == 0) rs2[tid >> 6] = s2;
  __syncthreads();
  if (tid == 0) {
    float l1 = (rs2[0] + rs2[1] + rs2[2] + rs2[3]) * (1.0f / GG);
    outp[0] = 0.01f * wsreg[0] + 0.01f * l1;
  }
}

extern "C" void kernel_launch(void* const* d_in, const int* in_sizes, int n_in,
                              void* d_out, int out_size, void* d_ws, size_t ws_size,
                              hipStream_t stream) {
  (void)in_sizes; (void)n_in; (void)out_size; (void)ws_size;
  const float* x    = (const float*)d_in[0];
  const int*   ei   = (const int*)d_in[1];
  const int*   mask = (const int*)d_in[2];
  const float* s    = (const float*)d_in[3];
  const float* Wn   = (const float*)d_in[5];
  const float* bn   = (const float*)d_in[6];
  const float* Wo   = (const float*)d_in[7];
  const float* bo   = (const float*)d_in[8];
  const float* Wr   = (const float*)d_in[9];
  const float* lng  = (const float*)d_in[10];
  const float* lnb  = (const float*)d_in[11];
  const float* flng = (const float*)d_in[12];
  const float* flnb = (const float*)d_in[13];
  const float* linw = (const float*)d_in[14];
  const float* bias = (const float*)d_in[15];
  float* out = (float*)d_out;

  char* ws = (char*)d_ws;
  size_t off = 0;
  auto alloc = [&](size_t b) { char* p = ws + off; off += (b + 255) & ~(size_t)255; return p; };
  unsigned short* Wnb = (unsigned short*)alloc((size_t)LLd * HD * HD * 2);
  unsigned short* Wob = (unsigned short*)alloc((size_t)LLd * HD * HD * 2);
  unsigned short* Wrb = (unsigned short*)alloc((size_t)LLd * HD * HD * 2);
  float* l1g    = (float*)alloc((size_t)GG * 4);
  float* wsreg  = (float*)alloc(256);

  const int* srcA = ei;
  const int* tgtA = ei + EE;

  hipMemsetAsync(wsreg, 0, 4, stream);
  convert_w_kernel<<<LLd * HD * HD / (256 * 4), 256, 0, stream>>>(Wn, Wo, Wr, bo,
      (unsigned*)Wnb, (unsigned*)Wob, (unsigned*)Wrb, wsreg);
  fused_kernel<<<GG, 512, 0, stream>>>(x, srcA, tgtA, mask, Wnb, Wob, Wrb, bn, bo,
                                       lng, lnb, s, flng, flnb, linw, bias, out, l1g);
  combine_kernel<<<1, 256, 0, stream>>>(l1g, wsreg, out + 256);
}

// Round 9
// 181.905 us; speedup vs baseline: 1.0931x; 1.0931x over previous
//
#include <hip/hip_runtime.h>

#define NN   32768
#define HD   128
#define EE   524288
#define GG   256
#define EPG  2048
#define CCd  16
#define LLd  3

typedef short short8 __attribute__((ext_vector_type(8)));   // 8 bf16 = 4 VGPRs
typedef float f32x4 __attribute__((ext_vector_type(4)));

__device__ __forceinline__ unsigned short f2bf(float f) {
  unsigned u = __builtin_bit_cast(unsigned, f);
  return (unsigned short)((u + 0x7FFFu + ((u >> 16) & 1u)) >> 16);  // RNE
}
__device__ __forceinline__ unsigned bfpack(float a, float b) {
  return (unsigned)f2bf(a) | ((unsigned)f2bf(b) << 16);
}

// hTs layout: [f][t] bf16, stride 128 (no pad), 16-B chunks XOR-swizzled:
//   phys = (c&8) | ((c ^ f ^ (f>>3)) & 7),  c = t>>3
__device__ __forceinline__ int hchunk(int f, int c) {
  return f * 128 + (((c & 8) | ((c ^ f ^ (f >> 3)) & 7)) << 3);
}
__device__ __forceinline__ int hidx(int f, int t) {
  return hchunk(f, t >> 3) + (t & 7);
}

// ---------------- convert weights to bf16 + reg_loss accumulate ----------------
__global__ __launch_bounds__(256) void convert_w_kernel(const float* __restrict__ Wn, const float* __restrict__ Wo,
                                                        const float* __restrict__ Wr, const float* __restrict__ bo,
                                                        unsigned* __restrict__ Wnb, unsigned* __restrict__ Wob,
                                                        unsigned* __restrict__ Wrb, float* __restrict__ wsreg) {
  int i = blockIdx.x * 256 + threadIdx.x;   // 48 blocks; 4 floats per array per thread
  float4 a = *(const float4*)(Wn + (size_t)i * 4);
  float4 b = *(const float4*)(Wo + (size_t)i * 4);
  float4 c = *(const float4*)(Wr + (size_t)i * 4);
  *(uint2*)(Wnb + (size_t)i * 2) = make_uint2(bfpack(a.x, a.y), bfpack(a.z, a.w));
  *(uint2*)(Wob + (size_t)i * 2) = make_uint2(bfpack(b.x, b.y), bfpack(b.z, b.w));
  *(uint2*)(Wrb + (size_t)i * 2) = make_uint2(bfpack(c.x, c.y), bfpack(c.z, c.w));
  float s = fabsf(b.x) + fabsf(b.y) + fabsf(b.z) + fabsf(b.w);
  if (blockIdx.x == 0 && threadIdx.x < 96) {       // 384 bo elements
    float4 d = *(const float4*)(bo + threadIdx.x * 4);
    s += fabsf(d.x) + fabsf(d.y) + fabsf(d.z) + fabsf(d.w);
  }
#pragma unroll
  for (int mk = 1; mk < 64; mk <<= 1) s += __shfl_xor(s, mk, 64);
  if ((threadIdx.x & 63) == 0) atomicAdd(wsreg, s);
}

// ---------------- fully fused per-graph network ----------------
// grid 256 (1 block/graph), 512 threads (8 waves; wave w owns node rows [16w,16w+16)).
// KEY LESSON (r6-r8): the allocator pins this kernel at 128 VGPRs regardless of
// __launch_bounds__ second arg; any structure demanding more (e.g. 48 W-prefetch
// regs) spills accumulators (WRITE_SIZE 80MB signature). Fix: W staging via
// __builtin_amdgcn_global_load_lds = ZERO registers. LDS dest is linear in lane
// order (HW constraint, m104); the XOR swizzle is pre-applied to the per-lane
// GLOBAL source address (m173 pattern), so wfrag's swizzled reads still work.
// Structure: (a) M B-frags in 32 persistent VGPRs; (b) THREE resident W slots
// (Wlds=Wn, Mlds-lo=Wo, Mlds-hi=Wr) -> 2 barriers/layer; restock gloads issue at
// bar1, land under the epilogue, drained by bar2's vmcnt(0).
__global__ __launch_bounds__(512) void fused_kernel(
    const float* __restrict__ x,
    const int* __restrict__ esrc, const int* __restrict__ etgt, const int* __restrict__ emask,
    const unsigned short* __restrict__ Wnb, const unsigned short* __restrict__ Wob,
    const unsigned short* __restrict__ Wrb,
    const float* __restrict__ bn, const float* __restrict__ bo,
    const float* __restrict__ lng, const float* __restrict__ lnb,
    const float* __restrict__ s,
    const float* __restrict__ flng, const float* __restrict__ flnb,
    const float* __restrict__ linw, const float* __restrict__ bias,
    float* __restrict__ out, float* __restrict__ l1g) {
  __shared__ __align__(16) unsigned short hTs[128 * 128];  // 32.0 KB  h^T, XOR-swizzled
  __shared__ __align__(16) unsigned short sTs[16 * 136];   //  4.3 KB  s^T [c][t]
  __shared__ __align__(16) unsigned Mlds[2 * 128 * 64];    // 64.0 KB  counts -> W slots B,C; pool scratch
  __shared__ __align__(16) unsigned Wlds[128 * 64];        // 32.0 KB  W slot A
  __shared__ float finS[128], foutS[128];
  __shared__ float colsumS[CCd], xcs[CCd], axcs[CCd], msk[CCd];

  const int g = blockIdx.x;
  const int tid = threadIdx.x;
  const int wave = tid >> 6;
  const int lane = tid & 63;
  const int m = lane & 15;
  const int q = lane >> 4;
  const int t0 = wave << 4;

  unsigned* const slotB = Mlds;          // Wo resident
  unsigned* const slotC = Mlds + 8192;   // Wr resident

  // ---- async W staging: global bf16 -> swizzled LDS slot, ZERO VGPRs ----
  // Call c covers rows [32c,32c+32); wave w writes rows 32c+4w..+3 (1 KB, linear
  // in lane order). Lane l: LDS phys chunk = l&15; global source logical chunk
  // lc = (l&15) ^ (row&7)  == the inverse of wfrag's read swizzle.
  auto w_stage = [&](const unsigned short* __restrict__ Wg, unsigned* slot) {
#pragma unroll
    for (int c = 0; c < 4; ++c) {
      int row = c * 32 + wave * 4 + (lane >> 4);
      int lc = (lane & 15) ^ (row & 7);
      const unsigned short* gp = Wg + row * 128 + lc * 8;   // 16 B = 8 bf16
      unsigned* lp = slot + c * 2048 + wave * 256;          // wave-uniform base
      __builtin_amdgcn_global_load_lds(
          (const __attribute__((address_space(1))) unsigned*)gp,
          (__attribute__((address_space(3))) unsigned*)lp, 16, 0, 0);
    }
  };
  // B-frag read from a W slot (swizzle matches w_stage; row&7 == m&7)
  auto wfrag = [&](const unsigned* slot, int ct, int ksg) -> short8 {
    return *(const short8*)&slot[(ct * 16 + m) * 64 + (((ksg * 4 + q) ^ (m & 7)) << 2)];
  };

  // ---- entry: Wn[0] -> Wlds async; edge loads into regs (latency under phase 0) ----
  w_stage(Wnb, Wlds);
  int et[4], es[4], em[4];
  {
    const int e0 = g * EPG;
#pragma unroll
    for (int i = 0; i < 4; ++i) {
      int e = e0 + i * 512 + tid;
      et[i] = etgt[e]; es[i] = esrc[e]; em[i] = emask[e];
    }
  }

  // ---- phase 0: zero counts + stage x->hTs (swizzled), s->sTs, colsum ----
  {
    uint4* cz = (uint4*)Mlds;   // 4096 uint4
#pragma unroll
    for (int i = 0; i < 8; ++i) cz[i * 512 + tid] = make_uint4(0u, 0u, 0u, 0u);

    const float4* xg = (const float4*)(x + (size_t)g * 16384);
#pragma unroll
    for (int i = 0; i < 8; ++i) {
      int flat = i * 512 + tid;           // 4096 float4s, fully coalesced
      int t = flat >> 5, f0 = (flat & 31) << 2;
      float4 v = xg[flat];
      hTs[hidx(f0 + 0, t)] = f2bf(v.x);
      hTs[hidx(f0 + 1, t)] = f2bf(v.y);
      hTs[hidx(f0 + 2, t)] = f2bf(v.z);
      hTs[hidx(f0 + 3, t)] = f2bf(v.w);
    }
    {
      int t = tid >> 2, c0 = (tid & 3) << 2;
      float4 v = *(const float4*)(s + (size_t)g * 2048 + t * 16 + c0);
      sTs[(c0 + 0) * 136 + t] = f2bf(v.x);
      sTs[(c0 + 1) * 136 + t] = f2bf(v.y);
      sTs[(c0 + 2) * 136 + t] = f2bf(v.z);
      sTs[(c0 + 3) * 136 + t] = f2bf(v.w);
    }
    if (tid < 64) {            // colsum: 4 lanes per column
      int c = tid & 15, qq = tid >> 4;
      float cs = 0.f;
      for (int tt = qq; tt < 128; tt += 4) cs += s[(size_t)g * 2048 + tt * 16 + c];
      cs += __shfl_xor(cs, 16); cs += __shfl_xor(cs, 32);
      if (qq == 0) colsumS[c] = cs;
    }
  }
  __syncthreads();

  // ---- phase 1: edge binning from prefetched regs, swizzled quads ----
  {
#pragma unroll
    for (int i = 0; i < 4; ++i) {
      int t = et[i] & 127;
      int sl = es[i] & 127;
      int dir = (em[i] != 0) ? 0 : 1;
      atomicAdd(&Mlds[dir * 8192 + t * 64 + (((sl >> 3) ^ (t & 7)) << 2) + ((sl >> 1) & 3)],
                1u << ((sl & 1) * 16));
    }
  }
  __syncthreads();

  // ---- phase 2: degrees + extract own M B-frags to registers (no LDS writes) ----
  short8 mfr[2][4];   // [dir][ksg] : M[t0+m][k=ksg*32+q*8+j] * inv, bf16
  {
    const int t = t0 + m;
    const int mm = m & 7;
    unsigned nin = 0, nout = 0;
#pragma unroll
    for (int k4 = 0; k4 < 4; ++k4) {
      int sl = (((q * 4 + k4) ^ mm) & 15) << 2;
      uint4 a = *(const uint4*)&Mlds[t * 64 + sl];
      uint4 b = *(const uint4*)&Mlds[8192 + t * 64 + sl];
      nin  += (a.x & 0xffffu) + (a.x >> 16) + (a.y & 0xffffu) + (a.y >> 16)
            + (a.z & 0xffffu) + (a.z >> 16) + (a.w & 0xffffu) + (a.w >> 16);
      nout += (b.x & 0xffffu) + (b.x >> 16) + (b.y & 0xffffu) + (b.y >> 16)
            + (b.z & 0xffffu) + (b.z >> 16) + (b.w & 0xffffu) + (b.w >> 16);
    }
    nin  += __shfl_xor((int)nin, 16);  nin  += __shfl_xor((int)nin, 32);
    nout += __shfl_xor((int)nout, 16); nout += __shfl_xor((int)nout, 32);
    unsigned dg = nin + nout;
    float inv = 1.0f / (float)(dg > 0 ? dg : 1);
    if (q == 0) { finS[t] = (float)nin * inv; foutS[t] = (float)nout * inv; }
#pragma unroll
    for (int d = 0; d < 2; ++d)
#pragma unroll
      for (int ksg = 0; ksg < 4; ++ksg) {
        int sl = (((ksg * 4 + q) ^ mm) & 15) << 2;   // logical chunk ksg*4+q
        uint4 v = *(const uint4*)&Mlds[d * 8192 + t * 64 + sl];
        uint4 o;
        o.x = bfpack((float)(v.x & 0xffffu) * inv, (float)(v.x >> 16) * inv);
        o.y = bfpack((float)(v.y & 0xffffu) * inv, (float)(v.y >> 16) * inv);
        o.z = bfpack((float)(v.z & 0xffffu) * inv, (float)(v.z >> 16) * inv);
        o.w = bfpack((float)(v.w & 0xffffu) * inv, (float)(v.w >> 16) * inv);
        mfr[d][ksg] = __builtin_bit_cast(short8, o);
      }
  }
  __syncthreads();   // all count reads done -> Mlds reusable as W slots

  // ---- async-fill slots B,C (Wo[0], Wr[0]); barrier drains vmcnt -> ready ----
  w_stage(Wob, slotB);
  w_stage(Wrb, slotC);
  __syncthreads();

  // ---- layers: 2 barriers each ----
  for (int L = 0; L < LLd; ++L) {
    const bool more = (L < LLd - 1);
    f32x4 pre[8];
#pragma unroll
    for (int ct = 0; ct < 8; ++ct) pre[ct] = (f32x4){0.f, 0.f, 0.f, 0.f};
    f32x4 accT[8];

#pragma unroll
    for (int sg = 0; sg < 2; ++sg) {
      const unsigned* slot = (sg == 0) ? (const unsigned*)Wlds : (const unsigned*)slotB;
      // --- M phase: accT[ft] = (Agg^T)[f-tile][t-slice], B-frags from registers ---
#pragma unroll
      for (int ft = 0; ft < 8; ++ft) accT[ft] = (f32x4){0.f, 0.f, 0.f, 0.f};
#pragma unroll
      for (int hf = 0; hf < 2; ++hf)
#pragma unroll
        for (int ksl = 0; ksl < 2; ++ksl) {
          const int ksg = hf * 2 + ksl;
          short8 bfr = mfr[sg][ksg];
#pragma unroll
          for (int ft = 0; ft < 8; ++ft) {
            short8 afr = *(const short8*)&hTs[hchunk(ft * 16 + m, ksg * 4 + q)];
            accT[ft] = __builtin_amdgcn_mfma_f32_16x16x32_bf16(afr, bfr, accT[ft], 0, 0, 0);
          }
        }
      // --- main phase: pre += Agg * W^T (packed single-shfl transpose; B from slot) ---
#pragma unroll
      for (int hf = 0; hf < 2; ++hf)
#pragma unroll
        for (int ksl = 0; ksl < 2; ++ksl) {
          const int ksg = hf * 2 + ksl;
          f32x4 lo = accT[2 * ksg], hi = accT[2 * ksg + 1];
          unsigned pk[4];
#pragma unroll
          for (int r = 0; r < 4; ++r) pk[r] = bfpack(lo[r], hi[r]);
          short8 afr;
#pragma unroll
          for (int j = 0; j < 8; ++j) {
            int srcl = ((((q & 1) << 1) + (j >> 2)) << 4) + m;
            unsigned v = (unsigned)__shfl((int)pk[j & 3], srcl, 64);
            afr[j] = (short)(unsigned short)((q >> 1) ? (v >> 16) : (v & 0xffffu));
          }
#pragma unroll
          for (int ct = 0; ct < 8; ++ct) {
            short8 bfr = wfrag(slot, ct, ksg);
            pre[ct] = __builtin_amdgcn_mfma_f32_16x16x32_bf16(afr, bfr, pre[ct], 0, 0, 0);
          }
        }
    }
    // --- Wr segment: A-frags scalar-read from hTs, B from slot C ---
#pragma unroll
    for (int hf = 0; hf < 2; ++hf)
#pragma unroll
      for (int ksl = 0; ksl < 2; ++ksl) {
        const int ksg = hf * 2 + ksl;
        short8 afr;
#pragma unroll
        for (int j = 0; j < 8; ++j)
          afr[j] = (short)hTs[hidx(ksg * 32 + q * 8 + j, t0 + m)];
#pragma unroll
        for (int ct = 0; ct < 8; ++ct) {
          short8 bfr = wfrag(slotC, ct, ksg);
          pre[ct] = __builtin_amdgcn_mfma_f32_16x16x32_bf16(afr, bfr, pre[ct], 0, 0, 0);
        }
      }
    __syncthreads();   // bar1: all hTs + W-slot reads of this layer done
    if (more) {        // async restock, zero regs; lands under epilogue; bar2 drains
      w_stage(Wnb + (L + 1) * 16384, Wlds);
      w_stage(Wob + (L + 1) * 16384, slotB);
      w_stage(Wrb + (L + 1) * 16384, slotC);
    }
    // --- epilogue: bias mix + LN + ReLU -> hTs (own wave's t-columns: race-free) ---
    {
      float bnv[8], bov[8], gv[8], bv[8];
#pragma unroll
      for (int ct = 0; ct < 8; ++ct) {
        int c = L * 128 + ct * 16 + m;
        bnv[ct] = bn[c]; bov[ct] = bo[c]; gv[ct] = lng[c]; bv[ct] = lnb[c];
      }
#pragma unroll
      for (int r = 0; r < 4; ++r) {
        const int tl = q * 4 + r;
        const float fiv = finS[t0 + tl], fov = foutS[t0 + tl];
        float v[8];
        float sum = 0.f;
#pragma unroll
        for (int ct = 0; ct < 8; ++ct) {
          v[ct] = pre[ct][r] + fiv * bnv[ct] + fov * bov[ct];
          sum += v[ct];
        }
        sum += __shfl_xor(sum, 1); sum += __shfl_xor(sum, 2);
        sum += __shfl_xor(sum, 4); sum += __shfl_xor(sum, 8);
        const float mu = sum * (1.0f / 128.0f);
        float sq = 0.f;
#pragma unroll
        for (int ct = 0; ct < 8; ++ct) { float d = v[ct] - mu; sq += d * d; }
        sq += __shfl_xor(sq, 1); sq += __shfl_xor(sq, 2);
        sq += __shfl_xor(sq, 4); sq += __shfl_xor(sq, 8);
        const float rstd = rsqrtf(sq * (1.0f / 128.0f) + 1e-5f);
#pragma unroll
        for (int ct = 0; ct < 8; ++ct) {
          float o = fmaxf((v[ct] - mu) * rstd * gv[ct] + bv[ct], 0.0f);
          hTs[hidx(ct * 16 + m, t0 + tl)] = f2bf(o);
        }
      }
    }
    __syncthreads();   // bar2: hTs visible + restock gloads drained (vmcnt 0)
  }

  // ---- pool: pooled[c][fo] = sum_t s[t][c]*h[t][fo]; wave w does fo-tile w ----
  f32x4 pl = (f32x4){0.f, 0.f, 0.f, 0.f};
#pragma unroll
  for (int ks = 0; ks < 4; ++ks) {
    short8 a = *(const short8*)&sTs[m * 136 + ks * 32 + q * 8];
    short8 b = *(const short8*)&hTs[hchunk(wave * 16 + m, ks * 4 + q)];
    pl = __builtin_amdgcn_mfma_f32_16x16x32_bf16(a, b, pl, 0, 0, 0);
  }
  float* pooledS = (float*)Mlds;   // W slots dead after last layer
#pragma unroll
  for (int r = 0; r < 4; ++r) pooledS[(q * 4 + r) * 132 + wave * 16 + m] = pl[r];
  __syncthreads();

  // ---- final LN + lin + mask (threads 0..255) ----
  if (tid < 256) {
    const int c = tid >> 4;
    const int j0 = (tid & 15) << 3;
    float v[8];
#pragma unroll
    for (int jj = 0; jj < 8; ++jj) v[jj] = pooledS[c * 132 + j0 + jj];
    float sum = 0.f;
#pragma unroll
    for (int jj = 0; jj < 8; ++jj) sum += v[jj];
#pragma unroll
    for (int mk = 1; mk < 16; mk <<= 1) sum += __shfl_xor(sum, mk, 64);
    float mu = sum * (1.0f / 128.0f);
    float sq = 0.f;
#pragma unroll
    for (int jj = 0; jj < 8; ++jj) { float d = v[jj] - mu; sq += d * d; }
#pragma unroll
    for (int mk = 1; mk < 16; mk <<= 1) sq += __shfl_xor(sq, mk, 64);
    float rstd = rsqrtf(sq * (1.0f / 128.0f) + 1e-5f);
    float dot = 0.f;
#pragma unroll
    for (int jj = 0; jj < 8; ++jj) {
      float nv = (v[jj] - mu) * rstd * flng[j0 + jj] + flnb[j0 + jj];
      dot += nv * linw[j0 + jj];
    }
#pragma unroll
    for (int mk = 1; mk < 16; mk <<= 1) dot += __shfl_xor(dot, mk, 64);
    if ((tid & 15) == 0) {
      float cm = (colsumS[c] > 0.f) ? 1.0f : 0.0f;
      float xcv = dot * cm;
      out[257 + g * CCd + c] = xcv;
      xcs[c] = xcv; axcs[c] = fabsf(xcv); msk[c] = cm;
    }
  }
  __syncthreads();
  if (tid == 0) {
    float so = 0.f, sa = 0.f, sd = 0.f;
#pragma unroll
    for (int k = 0; k < CCd; ++k) { so += xcs[k]; sa += axcs[k]; sd += msk[k] + 1e-7f; }
    out[g] = so + bias[0];
    l1g[g] = sa / sd;
  }
}

// ---------------- combine: losses = 0.01*reg + 0.01*mean_g(l1g) ----------------
__global__ __launch_bounds__(256) void combine_kernel(const float* __restrict__ l1g, const float* __restrict__ wsreg,
                                                      float* __restrict__ outp) {
  const int tid = threadIdx.x;
  float s2 = l1g[tid];
#pragma unroll
  for (int mk = 1; mk < 64; mk <<= 1) s2 += __shfl_xor(s2, mk, 64);
  __shared__ float rs2[4];
  if ((tid & 63) == 0) rs2[tid >> 6] = s2;
  __syncthreads();
  if (tid == 0) {
    float l1 = (rs2[0] + rs2[1] + rs2[2] + rs2[3]) * (1.0f / GG);
    outp[0] = 0.01f * wsreg[0] + 0.01f * l1;
  }
}

extern "C" void kernel_launch(void* const* d_in, const int* in_sizes, int n_in,
                              void* d_out, int out_size, void* d_ws, size_t ws_size,
                              hipStream_t stream) {
  (void)in_sizes; (void)n_in; (void)out_size; (void)ws_size;
  const float* x    = (const float*)d_in[0];
  const int*   ei   = (const int*)d_in[1];
  const int*   mask = (const int*)d_in[2];
  const float* s    = (const float*)d_in[3];
  const float* Wn   = (const float*)d_in[5];
  const float* bn   = (const float*)d_in[6];
  const float* Wo   = (const float*)d_in[7];
  const float* bo   = (const float*)d_in[8];
  const float* Wr   = (const float*)d_in[9];
  const float* lng  = (const float*)d_in[10];
  const float* lnb  = (const float*)d_in[11];
  const float* flng = (const float*)d_in[12];
  const float* flnb = (const float*)d_in[13];
  const float* linw = (const float*)d_in[14];
  const float* bias = (const float*)d_in[15];
  float* out = (float*)d_out;

  char* ws = (char*)d_ws;
  size_t off = 0;
  auto alloc = [&](size_t b) { char* p = ws + off; off += (b + 255) & ~(size_t)255; return p; };
  unsigned short* Wnb = (unsigned short*)alloc((size_t)LLd * HD * HD * 2);
  unsigned short* Wob = (unsigned short*)alloc((size_t)LLd * HD * HD * 2);
  unsigned short* Wrb = (unsigned short*)alloc((size_t)LLd * HD * HD * 2);
  float* l1g    = (float*)alloc((size_t)GG * 4);
  float* wsreg  = (float*)alloc(256);

  const int* srcA = ei;
  const int* tgtA = ei + EE;

  hipMemsetAsync(wsreg, 0, 4, stream);
  convert_w_kernel<<<LLd * HD * HD / (256 * 4), 256, 0, stream>>>(Wn, Wo, Wr, bo,
      (unsigned*)Wnb, (unsigned*)Wob, (unsigned*)Wrb, wsreg);
  fused_kernel<<<GG, 512, 0, stream>>>(x, srcA, tgtA, mask, Wnb, Wob, Wrb, bn, bo,
                                       lng, lnb, s, flng, flnb, linw, bias, out, l1g);
  combine_kernel<<<1, 256, 0, stream>>>(l1g, wsreg, out + 256);
}

// Round 10
// 177.235 us; speedup vs baseline: 1.1219x; 1.0264x over previous
//
#include <hip/hip_runtime.h>

#define NN   32768
#define HD   128
#define EE   524288
#define GG   256
#define EPG  2048
#define CCd  16
#define LLd  3

typedef short short8 __attribute__((ext_vector_type(8)));   // 8 bf16 = 4 VGPRs
typedef float f32x4 __attribute__((ext_vector_type(4)));

__device__ __forceinline__ unsigned short f2bf(float f) {
  unsigned u = __builtin_bit_cast(unsigned, f);
  return (unsigned short)((u + 0x7FFFu + ((u >> 16) & 1u)) >> 16);  // RNE
}
__device__ __forceinline__ unsigned bfpack(float a, float b) {
  return (unsigned)f2bf(a) | ((unsigned)f2bf(b) << 16);
}

// hTs layout: [f][t] bf16, stride 128 (no pad), 16-B chunks XOR-swizzled:
//   phys = (c&8) | ((c ^ f ^ (f>>3)) & 7),  c = t>>3
__device__ __forceinline__ int hchunk(int f, int c) {
  return f * 128 + (((c & 8) | ((c ^ f ^ (f >> 3)) & 7)) << 3);
}
__device__ __forceinline__ int hidx(int f, int t) {
  return hchunk(f, t >> 3) + (t & 7);
}

// ---------------- convert weights to bf16 + reg_loss accumulate ----------------
__global__ __launch_bounds__(256) void convert_w_kernel(const float* __restrict__ Wn, const float* __restrict__ Wo,
                                                        const float* __restrict__ Wr, const float* __restrict__ bo,
                                                        unsigned* __restrict__ Wnb, unsigned* __restrict__ Wob,
                                                        unsigned* __restrict__ Wrb, float* __restrict__ wsreg) {
  int i = blockIdx.x * 256 + threadIdx.x;   // 48 blocks; 4 floats per array per thread
  float4 a = *(const float4*)(Wn + (size_t)i * 4);
  float4 b = *(const float4*)(Wo + (size_t)i * 4);
  float4 c = *(const float4*)(Wr + (size_t)i * 4);
  *(uint2*)(Wnb + (size_t)i * 2) = make_uint2(bfpack(a.x, a.y), bfpack(a.z, a.w));
  *(uint2*)(Wob + (size_t)i * 2) = make_uint2(bfpack(b.x, b.y), bfpack(b.z, b.w));
  *(uint2*)(Wrb + (size_t)i * 2) = make_uint2(bfpack(c.x, c.y), bfpack(c.z, c.w));
  float s = fabsf(b.x) + fabsf(b.y) + fabsf(b.z) + fabsf(b.w);
  if (blockIdx.x == 0 && threadIdx.x < 96) {       // 384 bo elements
    float4 d = *(const float4*)(bo + threadIdx.x * 4);
    s += fabsf(d.x) + fabsf(d.y) + fabsf(d.z) + fabsf(d.w);
  }
#pragma unroll
  for (int mk = 1; mk < 64; mk <<= 1) s += __shfl_xor(s, mk, 64);
  if ((threadIdx.x & 63) == 0) atomicAdd(wsreg, s);
}

// ---------------- fully fused per-graph network ----------------
// grid 256 (1 block/graph), 512 threads (8 waves; wave w owns node rows [16w,16w+16)).
// REGISTER BUDGET (r6-r9 lesson): allocator works within ~128 VGPRs here; demand
// above that spills accumulators (WRITE_SIZE tens-of-MB signature). This version
// splits the M-phase reduction so only TWO accT tiles (8 regs) are live at once:
// for each output fi-block kso: {partial M-phase (2 f-tiles, full t' reduction) ->
// transpose -> main-phase kso}. Identical MFMAs/indices to r9 (HW-verified), pure
// reorder. Peak = pre(32) + accT(8) + mfr(32) + transients ~= 110 < 128.
// W staging: __builtin_amdgcn_global_load_lds (zero regs), swizzle pre-applied to
// the per-lane GLOBAL source (m173); THREE resident W slots -> 2 barriers/layer.
__global__ __launch_bounds__(512) void fused_kernel(
    const float* __restrict__ x,
    const int* __restrict__ esrc, const int* __restrict__ etgt, const int* __restrict__ emask,
    const unsigned short* __restrict__ Wnb, const unsigned short* __restrict__ Wob,
    const unsigned short* __restrict__ Wrb,
    const float* __restrict__ bn, const float* __restrict__ bo,
    const float* __restrict__ lng, const float* __restrict__ lnb,
    const float* __restrict__ s,
    const float* __restrict__ flng, const float* __restrict__ flnb,
    const float* __restrict__ linw, const float* __restrict__ bias,
    float* __restrict__ out, float* __restrict__ l1g) {
  __shared__ __align__(16) unsigned short hTs[128 * 128];  // 32.0 KB  h^T, XOR-swizzled
  __shared__ __align__(16) unsigned short sTs[16 * 136];   //  4.3 KB  s^T [c][t]
  __shared__ __align__(16) unsigned Mlds[2 * 128 * 64];    // 64.0 KB  counts -> W slots B,C; pool scratch
  __shared__ __align__(16) unsigned Wlds[128 * 64];        // 32.0 KB  W slot A
  __shared__ float finS[128], foutS[128];
  __shared__ float colsumS[CCd], xcs[CCd], axcs[CCd], msk[CCd];

  const int g = blockIdx.x;
  const int tid = threadIdx.x;
  const int wave = tid >> 6;
  const int lane = tid & 63;
  const int m = lane & 15;
  const int q = lane >> 4;
  const int t0 = wave << 4;

  unsigned* const slotB = Mlds;          // Wo resident
  unsigned* const slotC = Mlds + 8192;   // Wr resident

  // ---- async W staging: global bf16 -> swizzled LDS slot, ZERO VGPRs ----
  auto w_stage = [&](const unsigned short* __restrict__ Wg, unsigned* slot) {
#pragma unroll
    for (int c = 0; c < 4; ++c) {
      int row = c * 32 + wave * 4 + (lane >> 4);
      int lc = (lane & 15) ^ (row & 7);
      const unsigned short* gp = Wg + row * 128 + lc * 8;   // 16 B = 8 bf16
      unsigned* lp = slot + c * 2048 + wave * 256;          // wave-uniform base
      __builtin_amdgcn_global_load_lds(
          (const __attribute__((address_space(1))) unsigned*)gp,
          (__attribute__((address_space(3))) unsigned*)lp, 16, 0, 0);
    }
  };
  // B-frag read from a W slot (swizzle matches w_stage; row&7 == m&7)
  auto wfrag = [&](const unsigned* slot, int ct, int ksg) -> short8 {
    return *(const short8*)&slot[(ct * 16 + m) * 64 + (((ksg * 4 + q) ^ (m & 7)) << 2)];
  };

  // ---- entry: Wn[0] -> Wlds async; edge loads into regs (latency under phase 0) ----
  w_stage(Wnb, Wlds);
  int et[4], es[4], em[4];
  {
    const int e0 = g * EPG;
#pragma unroll
    for (int i = 0; i < 4; ++i) {
      int e = e0 + i * 512 + tid;
      et[i] = etgt[e]; es[i] = esrc[e]; em[i] = emask[e];
    }
  }

  // ---- phase 0: zero counts + stage x->hTs (swizzled), s->sTs, colsum ----
  {
    uint4* cz = (uint4*)Mlds;   // 4096 uint4
#pragma unroll
    for (int i = 0; i < 8; ++i) cz[i * 512 + tid] = make_uint4(0u, 0u, 0u, 0u);

    const float4* xg = (const float4*)(x + (size_t)g * 16384);
#pragma unroll
    for (int i = 0; i < 8; ++i) {
      int flat = i * 512 + tid;           // 4096 float4s, fully coalesced
      int t = flat >> 5, f0 = (flat & 31) << 2;
      float4 v = xg[flat];
      hTs[hidx(f0 + 0, t)] = f2bf(v.x);
      hTs[hidx(f0 + 1, t)] = f2bf(v.y);
      hTs[hidx(f0 + 2, t)] = f2bf(v.z);
      hTs[hidx(f0 + 3, t)] = f2bf(v.w);
    }
    {
      int t = tid >> 2, c0 = (tid & 3) << 2;
      float4 v = *(const float4*)(s + (size_t)g * 2048 + t * 16 + c0);
      sTs[(c0 + 0) * 136 + t] = f2bf(v.x);
      sTs[(c0 + 1) * 136 + t] = f2bf(v.y);
      sTs[(c0 + 2) * 136 + t] = f2bf(v.z);
      sTs[(c0 + 3) * 136 + t] = f2bf(v.w);
    }
    if (tid < 64) {            // colsum: 4 lanes per column
      int c = tid & 15, qq = tid >> 4;
      float cs = 0.f;
      for (int tt = qq; tt < 128; tt += 4) cs += s[(size_t)g * 2048 + tt * 16 + c];
      cs += __shfl_xor(cs, 16); cs += __shfl_xor(cs, 32);
      if (qq == 0) colsumS[c] = cs;
    }
  }
  __syncthreads();

  // ---- phase 1: edge binning from prefetched regs, swizzled quads ----
  {
#pragma unroll
    for (int i = 0; i < 4; ++i) {
      int t = et[i] & 127;
      int sl = es[i] & 127;
      int dir = (em[i] != 0) ? 0 : 1;
      atomicAdd(&Mlds[dir * 8192 + t * 64 + (((sl >> 3) ^ (t & 7)) << 2) + ((sl >> 1) & 3)],
                1u << ((sl & 1) * 16));
    }
  }
  __syncthreads();

  // ---- phase 2: degrees + extract own M B-frags to registers (no LDS writes) ----
  short8 mfr[2][4];   // [dir][ksg] : M[t0+m][k=ksg*32+q*8+j] * inv, bf16
  {
    const int t = t0 + m;
    const int mm = m & 7;
    unsigned nin = 0, nout = 0;
#pragma unroll
    for (int k4 = 0; k4 < 4; ++k4) {
      int sl = (((q * 4 + k4) ^ mm) & 15) << 2;
      uint4 a = *(const uint4*)&Mlds[t * 64 + sl];
      uint4 b = *(const uint4*)&Mlds[8192 + t * 64 + sl];
      nin  += (a.x & 0xffffu) + (a.x >> 16) + (a.y & 0xffffu) + (a.y >> 16)
            + (a.z & 0xffffu) + (a.z >> 16) + (a.w & 0xffffu) + (a.w >> 16);
      nout += (b.x & 0xffffu) + (b.x >> 16) + (b.y & 0xffffu) + (b.y >> 16)
            + (b.z & 0xffffu) + (b.z >> 16) + (b.w & 0xffffu) + (b.w >> 16);
    }
    nin  += __shfl_xor((int)nin, 16);  nin  += __shfl_xor((int)nin, 32);
    nout += __shfl_xor((int)nout, 16); nout += __shfl_xor((int)nout, 32);
    unsigned dg = nin + nout;
    float inv = 1.0f / (float)(dg > 0 ? dg : 1);
    if (q == 0) { finS[t] = (float)nin * inv; foutS[t] = (float)nout * inv; }
#pragma unroll
    for (int d = 0; d < 2; ++d)
#pragma unroll
      for (int ksg = 0; ksg < 4; ++ksg) {
        int sl = (((ksg * 4 + q) ^ mm) & 15) << 2;   // logical chunk ksg*4+q
        uint4 v = *(const uint4*)&Mlds[d * 8192 + t * 64 + sl];
        uint4 o;
        o.x = bfpack((float)(v.x & 0xffffu) * inv, (float)(v.x >> 16) * inv);
        o.y = bfpack((float)(v.y & 0xffffu) * inv, (float)(v.y >> 16) * inv);
        o.z = bfpack((float)(v.z & 0xffffu) * inv, (float)(v.z >> 16) * inv);
        o.w = bfpack((float)(v.w & 0xffffu) * inv, (float)(v.w >> 16) * inv);
        mfr[d][ksg] = __builtin_bit_cast(short8, o);
      }
  }
  __syncthreads();   // all count reads done -> Mlds reusable as W slots

  // ---- async-fill slots B,C (Wo[0], Wr[0]); barrier drains vmcnt -> ready ----
  w_stage(Wob, slotB);
  w_stage(Wrb, slotC);
  __syncthreads();

  // ---- layers: 2 barriers each ----
  for (int L = 0; L < LLd; ++L) {
    const bool more = (L < LLd - 1);
    f32x4 pre[8];
#pragma unroll
    for (int ct = 0; ct < 8; ++ct) pre[ct] = (f32x4){0.f, 0.f, 0.f, 0.f};

#pragma unroll
    for (int sg = 0; sg < 2; ++sg) {
      const unsigned* slot = (sg == 0) ? (const unsigned*)Wlds : (const unsigned*)slotB;
      // For each output fi-block kso: partial M-phase (2 f-tiles, 8 regs) ->
      // transpose -> main-phase kso. Only 8 accT regs live at any point.
#pragma unroll
      for (int kso = 0; kso < 4; ++kso) {
        f32x4 acc0 = (f32x4){0.f, 0.f, 0.f, 0.f};
        f32x4 acc1 = (f32x4){0.f, 0.f, 0.f, 0.f};
#pragma unroll
        for (int ksi = 0; ksi < 4; ++ksi) {
          short8 bfr = mfr[sg][ksi];
          short8 a0 = *(const short8*)&hTs[hchunk((2 * kso) * 16 + m, ksi * 4 + q)];
          acc0 = __builtin_amdgcn_mfma_f32_16x16x32_bf16(a0, bfr, acc0, 0, 0, 0);
          short8 a1 = *(const short8*)&hTs[hchunk((2 * kso + 1) * 16 + m, ksi * 4 + q)];
          acc1 = __builtin_amdgcn_mfma_f32_16x16x32_bf16(a1, bfr, acc1, 0, 0, 0);
        }
        // packed single-shfl transpose (identical math to r9, lo/hi = acc0/acc1)
        unsigned pk[4];
#pragma unroll
        for (int r = 0; r < 4; ++r) pk[r] = bfpack(acc0[r], acc1[r]);
        short8 afr;
#pragma unroll
        for (int j = 0; j < 8; ++j) {
          int srcl = ((((q & 1) << 1) + (j >> 2)) << 4) + m;
          unsigned v = (unsigned)__shfl((int)pk[j & 3], srcl, 64);
          afr[j] = (short)(unsigned short)((q >> 1) ? (v >> 16) : (v & 0xffffu));
        }
#pragma unroll
        for (int ct = 0; ct < 8; ++ct) {
          short8 bfr = wfrag(slot, ct, kso);
          pre[ct] = __builtin_amdgcn_mfma_f32_16x16x32_bf16(afr, bfr, pre[ct], 0, 0, 0);
        }
      }
    }
    // --- Wr segment: A-frags scalar-read from hTs, B from slot C ---
#pragma unroll
    for (int hf = 0; hf < 2; ++hf)
#pragma unroll
      for (int ksl = 0; ksl < 2; ++ksl) {
        const int ksg = hf * 2 + ksl;
        short8 afr;
#pragma unroll
        for (int j = 0; j < 8; ++j)
          afr[j] = (short)hTs[hidx(ksg * 32 + q * 8 + j, t0 + m)];
#pragma unroll
        for (int ct = 0; ct < 8; ++ct) {
          short8 bfr = wfrag(slotC, ct, ksg);
          pre[ct] = __builtin_amdgcn_mfma_f32_16x16x32_bf16(afr, bfr, pre[ct], 0, 0, 0);
        }
      }
    __syncthreads();   // bar1: all hTs + W-slot reads of this layer done
    if (more) {        // async restock, zero regs; lands under epilogue; bar2 drains
      w_stage(Wnb + (L + 1) * 16384, Wlds);
      w_stage(Wob + (L + 1) * 16384, slotB);
      w_stage(Wrb + (L + 1) * 16384, slotC);
    }
    // --- epilogue: bias mix + LN + ReLU -> hTs (own wave's t-columns: race-free) ---
    {
      float bnv[8], bov[8], gv[8], bv[8];
#pragma unroll
      for (int ct = 0; ct < 8; ++ct) {
        int c = L * 128 + ct * 16 + m;
        bnv[ct] = bn[c]; bov[ct] = bo[c]; gv[ct] = lng[c]; bv[ct] = lnb[c];
      }
#pragma unroll
      for (int r = 0; r < 4; ++r) {
        const int tl = q * 4 + r;
        const float fiv = finS[t0 + tl], fov = foutS[t0 + tl];
        float v[8];
        float sum = 0.f;
#pragma unroll
        for (int ct = 0; ct < 8; ++ct) {
          v[ct] = pre[ct][r] + fiv * bnv[ct] + fov * bov[ct];
          sum += v[ct];
        }
        sum += __shfl_xor(sum, 1); sum += __shfl_xor(sum, 2);
        sum += __shfl_xor(sum, 4); sum += __shfl_xor(sum, 8);
        const float mu = sum * (1.0f / 128.0f);
        float sq = 0.f;
#pragma unroll
        for (int ct = 0; ct < 8; ++ct) { float d = v[ct] - mu; sq += d * d; }
        sq += __shfl_xor(sq, 1); sq += __shfl_xor(sq, 2);
        sq += __shfl_xor(sq, 4); sq += __shfl_xor(sq, 8);
        const float rstd = rsqrtf(sq * (1.0f / 128.0f) + 1e-5f);
#pragma unroll
        for (int ct = 0; ct < 8; ++ct) {
          float o = fmaxf((v[ct] - mu) * rstd * gv[ct] + bv[ct], 0.0f);
          hTs[hidx(ct * 16 + m, t0 + tl)] = f2bf(o);
        }
      }
    }
    __syncthreads();   // bar2: hTs visible + restock gloads drained (vmcnt 0)
  }

  // ---- pool: pooled[c][fo] = sum_t s[t][c]*h[t][fo]; wave w does fo-tile w ----
  f32x4 pl = (f32x4){0.f, 0.f, 0.f, 0.f};
#pragma unroll
  for (int ks = 0; ks < 4; ++ks) {
    short8 a = *(const short8*)&sTs[m * 136 + ks * 32 + q * 8];
    short8 b = *(const short8*)&hTs[hchunk(wave * 16 + m, ks * 4 + q)];
    pl = __builtin_amdgcn_mfma_f32_16x16x32_bf16(a, b, pl, 0, 0, 0);
  }
  float* pooledS = (float*)Mlds;   // W slots dead after last layer
#pragma unroll
  for (int r = 0; r < 4; ++r) pooledS[(q * 4 + r) * 132 + wave * 16 + m] = pl[r];
  __syncthreads();

  // ---- final LN + lin + mask (threads 0..255) ----
  if (tid < 256) {
    const int c = tid >> 4;
    const int j0 = (tid & 15) << 3;
    float v[8];
#pragma unroll
    for (int jj = 0; jj < 8; ++jj) v[jj] = pooledS[c * 132 + j0 + jj];
    float sum = 0.f;
#pragma unroll
    for (int jj = 0; jj < 8; ++jj) sum += v[jj];
#pragma unroll
    for (int mk = 1; mk < 16; mk <<= 1) sum += __shfl_xor(sum, mk, 64);
    float mu = sum * (1.0f / 128.0f);
    float sq = 0.f;
#pragma unroll
    for (int jj = 0; jj < 8; ++jj) { float d = v[jj] - mu; sq += d * d; }
#pragma unroll
    for (int mk = 1; mk < 16; mk <<= 1) sq += __shfl_xor(sq, mk, 64);
    float rstd = rsqrtf(sq * (1.0f / 128.0f) + 1e-5f);
    float dot = 0.f;
#pragma unroll
    for (int jj = 0; jj < 8; ++jj) {
      float nv = (v[jj] - mu) * rstd * flng[j0 + jj] + flnb[j0 + jj];
      dot += nv * linw[j0 + jj];
    }
#pragma unroll
    for (int mk = 1; mk < 16; mk <<= 1) dot += __shfl_xor(dot, mk, 64);
    if ((tid & 15) == 0) {
      float cm = (colsumS[c] > 0.f) ? 1.0f : 0.0f;
      float xcv = dot * cm;
      out[257 + g * CCd + c] = xcv;
      xcs[c] = xcv; axcs[c] = fabsf(xcv); msk[c] = cm;
    }
  }
  __syncthreads();
  if (tid == 0) {
    float so = 0.f, sa = 0.f, sd = 0.f;
#pragma unroll
    for (int k = 0; k < CCd; ++k) { so += xcs[k]; sa += axcs[k]; sd += msk[k] + 1e-7f; }
    out[g] = so + bias[0];
    l1g[g] = sa / sd;
  }
}

// ---------------- combine: losses = 0.01*reg + 0.01*mean_g(l1g) ----------------
__global__ __launch_bounds__(256) void combine_kernel(const float* __restrict__ l1g, const float* __restrict__ wsreg,
                                                      float* __restrict__ outp) {
  const int tid = threadIdx.x;
  float s2 = l1g[tid];
#pragma unroll
  for (int mk = 1; mk < 64; mk <<= 1) s2 += __shfl_xor(s2, mk, 64);
  __shared__ float rs2[4];
  if ((tid & 63) == 0) rs2[tid >> 6] = s2;
  __syncthreads();
  if (tid == 0) {
    float l1 = (rs2[0] + rs2[1] + rs2[2] + rs2[3]) * (1.0f / GG);
    outp[0] = 0.01f * wsreg[0] + 0.01f * l1;
  }
}

extern "C" void kernel_launch(void* const* d_in, const int* in_sizes, int n_in,
                              void* d_out, int out_size, void* d_ws, size_t ws_size,
                              hipStream_t stream) {
  (void)in_sizes; (void)n_in; (void)out_size; (void)ws_size;
  const float* x    = (const float*)d_in[0];
  const int*   ei   = (const int*)d_in[1];
  const int*   mask = (const int*)d_in[2];
  const float* s    = (const float*)d_in[3];
  const float* Wn   = (const float*)d_in[5];
  const float* bn   = (const float*)d_in[6];
  const float* Wo   = (const float*)d_in[7];
  const float* bo   = (const float*)d_in[8];
  const float* Wr   = (const float*)d_in[9];
  const float* lng  = (const float*)d_in[10];
  const float* lnb  = (const float*)d_in[11];
  const float* flng = (const float*)d_in[12];
  const float* flnb = (const float*)d_in[13];
  const float* linw = (const float*)d_in[14];
  const float* bias = (const float*)d_in[15];
  float* out = (float*)d_out;

  char* ws = (char*)d_ws;
  size_t off = 0;
  auto alloc = [&](size_t b) { char* p = ws + off; off += (b + 255) & ~(size_t)255; return p; };
  unsigned short* Wnb = (unsigned short*)alloc((size_t)LLd * HD * HD * 2);
  unsigned short* Wob = (unsigned short*)alloc((size_t)LLd * HD * HD * 2);
  unsigned short* Wrb = (unsigned short*)alloc((size_t)LLd * HD * HD * 2);
  float* l1g    = (float*)alloc((size_t)GG * 4);
  float* wsreg  = (float*)alloc(256);

  const int* srcA = ei;
  const int* tgtA = ei + EE;

  hipMemsetAsync(wsreg, 0, 4, stream);
  convert_w_kernel<<<LLd * HD * HD / (256 * 4), 256, 0, stream>>>(Wn, Wo, Wr, bo,
      (unsigned*)Wnb, (unsigned*)Wob, (unsigned*)Wrb, wsreg);
  fused_kernel<<<GG, 512, 0, stream>>>(x, srcA, tgtA, mask, Wnb, Wob, Wrb, bn, bo,
                                       lng, lnb, s, flng, flnb, linw, bias, out, l1g);
  combine_kernel<<<1, 256, 0, stream>>>(l1g, wsreg, out + 256);
}

// Round 11
// 160.699 us; speedup vs baseline: 1.2373x; 1.1029x over previous
//
#include <hip/hip_runtime.h>

#define NN   32768
#define HD   128
#define EE   524288
#define GG   256
#define EPG  2048
#define CCd  16
#define LLd  3

typedef short short8 __attribute__((ext_vector_type(8)));   // 8 bf16 = 4 VGPRs
typedef float f32x4 __attribute__((ext_vector_type(4)));

__device__ __forceinline__ unsigned short f2bf(float f) {
  unsigned u = __builtin_bit_cast(unsigned, f);
  return (unsigned short)((u + 0x7FFFu + ((u >> 16) & 1u)) >> 16);  // RNE
}
__device__ __forceinline__ unsigned bfpack(float a, float b) {
  return (unsigned)f2bf(a) | ((unsigned)f2bf(b) << 16);
}

// hTs layout: [f][t] bf16, stride 128 (no pad), 16-B chunks XOR-swizzled:
//   phys = (c&8) | ((c ^ f ^ (f>>3)) & 7),  c = t>>3
__device__ __forceinline__ int hchunk(int f, int c) {
  return f * 128 + (((c & 8) | ((c ^ f ^ (f >> 3)) & 7)) << 3);
}
__device__ __forceinline__ int hidx(int f, int t) {
  return hchunk(f, t >> 3) + (t & 7);
}

// ---------------- convert weights to bf16 + reg_loss accumulate ----------------
__global__ __launch_bounds__(256) void convert_w_kernel(const float* __restrict__ Wn, const float* __restrict__ Wo,
                                                        const float* __restrict__ Wr, const float* __restrict__ bo,
                                                        unsigned* __restrict__ Wnb, unsigned* __restrict__ Wob,
                                                        unsigned* __restrict__ Wrb, float* __restrict__ wsreg) {
  int i = blockIdx.x * 256 + threadIdx.x;   // 48 blocks; 4 floats per array per thread
  float4 a = *(const float4*)(Wn + (size_t)i * 4);
  float4 b = *(const float4*)(Wo + (size_t)i * 4);
  float4 c = *(const float4*)(Wr + (size_t)i * 4);
  *(uint2*)(Wnb + (size_t)i * 2) = make_uint2(bfpack(a.x, a.y), bfpack(a.z, a.w));
  *(uint2*)(Wob + (size_t)i * 2) = make_uint2(bfpack(b.x, b.y), bfpack(b.z, b.w));
  *(uint2*)(Wrb + (size_t)i * 2) = make_uint2(bfpack(c.x, c.y), bfpack(c.z, c.w));
  float s = fabsf(b.x) + fabsf(b.y) + fabsf(b.z) + fabsf(b.w);
  if (blockIdx.x == 0 && threadIdx.x < 96) {       // 384 bo elements
    float4 d = *(const float4*)(bo + threadIdx.x * 4);
    s += fabsf(d.x) + fabsf(d.y) + fabsf(d.z) + fabsf(d.w);
  }
#pragma unroll
  for (int mk = 1; mk < 64; mk <<= 1) s += __shfl_xor(s, mk, 64);
  if ((threadIdx.x & 63) == 0) atomicAdd(wsreg, s);
}

// ---------------- fully fused per-graph network ----------------
// grid 256 (1 block/graph), 512 threads (8 waves; wave w owns node rows [16w,16w+16)).
// REGISTER MODEL (r6-r10): allocator budget ~128 VGPRs; exceeding it spills the
// persistent arrays (WRITE_SIZE tens-of-MB signature). r9/r10's identical 51.7MB
// across a main-phase rewrite localizes the overrun to the EPILOGUE (pre 32 +
// mfr 32 + bias/LN arrays 32 + v 8 ~= 136). This version: bias-mix folded into
// pre as a one-shot low-pressure pass (transient 4+4 regs, no LICM re-hoist),
// v[] eliminated (LN normalizes pre in place), only gv/bv (16) kept as arrays.
// Epilogue peak ~= 96 < 128. Everything else identical to r10: acc-split M-phase
// (8 accT regs), mfr in 32 persistent regs, zero-reg global_load_lds W staging
// (swizzle pre-applied to global source, m173), 3 resident W slots, 2 barriers/layer.
__global__ __launch_bounds__(512) void fused_kernel(
    const float* __restrict__ x,
    const int* __restrict__ esrc, const int* __restrict__ etgt, const int* __restrict__ emask,
    const unsigned short* __restrict__ Wnb, const unsigned short* __restrict__ Wob,
    const unsigned short* __restrict__ Wrb,
    const float* __restrict__ bn, const float* __restrict__ bo,
    const float* __restrict__ lng, const float* __restrict__ lnb,
    const float* __restrict__ s,
    const float* __restrict__ flng, const float* __restrict__ flnb,
    const float* __restrict__ linw, const float* __restrict__ bias,
    float* __restrict__ out, float* __restrict__ l1g) {
  __shared__ __align__(16) unsigned short hTs[128 * 128];  // 32.0 KB  h^T, XOR-swizzled
  __shared__ __align__(16) unsigned short sTs[16 * 136];   //  4.3 KB  s^T [c][t]
  __shared__ __align__(16) unsigned Mlds[2 * 128 * 64];    // 64.0 KB  counts -> W slots B,C; pool scratch
  __shared__ __align__(16) unsigned Wlds[128 * 64];        // 32.0 KB  W slot A
  __shared__ float finS[128], foutS[128];
  __shared__ float colsumS[CCd], xcs[CCd], axcs[CCd], msk[CCd];

  const int g = blockIdx.x;
  const int tid = threadIdx.x;
  const int wave = tid >> 6;
  const int lane = tid & 63;
  const int m = lane & 15;
  const int q = lane >> 4;
  const int t0 = wave << 4;

  unsigned* const slotB = Mlds;          // Wo resident
  unsigned* const slotC = Mlds + 8192;   // Wr resident

  // ---- async W staging: global bf16 -> swizzled LDS slot, ZERO VGPRs ----
  auto w_stage = [&](const unsigned short* __restrict__ Wg, unsigned* slot) {
#pragma unroll
    for (int c = 0; c < 4; ++c) {
      int row = c * 32 + wave * 4 + (lane >> 4);
      int lc = (lane & 15) ^ (row & 7);
      const unsigned short* gp = Wg + row * 128 + lc * 8;   // 16 B = 8 bf16
      unsigned* lp = slot + c * 2048 + wave * 256;          // wave-uniform base
      __builtin_amdgcn_global_load_lds(
          (const __attribute__((address_space(1))) unsigned*)gp,
          (__attribute__((address_space(3))) unsigned*)lp, 16, 0, 0);
    }
  };
  // B-frag read from a W slot (swizzle matches w_stage; row&7 == m&7)
  auto wfrag = [&](const unsigned* slot, int ct, int ksg) -> short8 {
    return *(const short8*)&slot[(ct * 16 + m) * 64 + (((ksg * 4 + q) ^ (m & 7)) << 2)];
  };

  // ---- entry: Wn[0] -> Wlds async; edge loads into regs (latency under phase 0) ----
  w_stage(Wnb, Wlds);
  int et[4], es[4], em[4];
  {
    const int e0 = g * EPG;
#pragma unroll
    for (int i = 0; i < 4; ++i) {
      int e = e0 + i * 512 + tid;
      et[i] = etgt[e]; es[i] = esrc[e]; em[i] = emask[e];
    }
  }

  // ---- phase 0: zero counts + stage x->hTs (swizzled), s->sTs, colsum ----
  {
    uint4* cz = (uint4*)Mlds;   // 4096 uint4
#pragma unroll
    for (int i = 0; i < 8; ++i) cz[i * 512 + tid] = make_uint4(0u, 0u, 0u, 0u);

    const float4* xg = (const float4*)(x + (size_t)g * 16384);
#pragma unroll
    for (int i = 0; i < 8; ++i) {
      int flat = i * 512 + tid;           // 4096 float4s, fully coalesced
      int t = flat >> 5, f0 = (flat & 31) << 2;
      float4 v = xg[flat];
      hTs[hidx(f0 + 0, t)] = f2bf(v.x);
      hTs[hidx(f0 + 1, t)] = f2bf(v.y);
      hTs[hidx(f0 + 2, t)] = f2bf(v.z);
      hTs[hidx(f0 + 3, t)] = f2bf(v.w);
    }
    {
      int t = tid >> 2, c0 = (tid & 3) << 2;
      float4 v = *(const float4*)(s + (size_t)g * 2048 + t * 16 + c0);
      sTs[(c0 + 0) * 136 + t] = f2bf(v.x);
      sTs[(c0 + 1) * 136 + t] = f2bf(v.y);
      sTs[(c0 + 2) * 136 + t] = f2bf(v.z);
      sTs[(c0 + 3) * 136 + t] = f2bf(v.w);
    }
    if (tid < 64) {            // colsum: 4 lanes per column
      int c = tid & 15, qq = tid >> 4;
      float cs = 0.f;
      for (int tt = qq; tt < 128; tt += 4) cs += s[(size_t)g * 2048 + tt * 16 + c];
      cs += __shfl_xor(cs, 16); cs += __shfl_xor(cs, 32);
      if (qq == 0) colsumS[c] = cs;
    }
  }
  __syncthreads();

  // ---- phase 1: edge binning from prefetched regs, swizzled quads ----
  {
#pragma unroll
    for (int i = 0; i < 4; ++i) {
      int t = et[i] & 127;
      int sl = es[i] & 127;
      int dir = (em[i] != 0) ? 0 : 1;
      atomicAdd(&Mlds[dir * 8192 + t * 64 + (((sl >> 3) ^ (t & 7)) << 2) + ((sl >> 1) & 3)],
                1u << ((sl & 1) * 16));
    }
  }
  __syncthreads();

  // ---- phase 2: degrees + extract own M B-frags to registers (no LDS writes) ----
  short8 mfr[2][4];   // [dir][ksg] : M[t0+m][k=ksg*32+q*8+j] * inv, bf16
  {
    const int t = t0 + m;
    const int mm = m & 7;
    unsigned nin = 0, nout = 0;
#pragma unroll
    for (int k4 = 0; k4 < 4; ++k4) {
      int sl = (((q * 4 + k4) ^ mm) & 15) << 2;
      uint4 a = *(const uint4*)&Mlds[t * 64 + sl];
      uint4 b = *(const uint4*)&Mlds[8192 + t * 64 + sl];
      nin  += (a.x & 0xffffu) + (a.x >> 16) + (a.y & 0xffffu) + (a.y >> 16)
            + (a.z & 0xffffu) + (a.z >> 16) + (a.w & 0xffffu) + (a.w >> 16);
      nout += (b.x & 0xffffu) + (b.x >> 16) + (b.y & 0xffffu) + (b.y >> 16)
            + (b.z & 0xffffu) + (b.z >> 16) + (b.w & 0xffffu) + (b.w >> 16);
    }
    nin  += __shfl_xor((int)nin, 16);  nin  += __shfl_xor((int)nin, 32);
    nout += __shfl_xor((int)nout, 16); nout += __shfl_xor((int)nout, 32);
    unsigned dg = nin + nout;
    float inv = 1.0f / (float)(dg > 0 ? dg : 1);
    if (q == 0) { finS[t] = (float)nin * inv; foutS[t] = (float)nout * inv; }
#pragma unroll
    for (int d = 0; d < 2; ++d)
#pragma unroll
      for (int ksg = 0; ksg < 4; ++ksg) {
        int sl = (((ksg * 4 + q) ^ mm) & 15) << 2;   // logical chunk ksg*4+q
        uint4 v = *(const uint4*)&Mlds[d * 8192 + t * 64 + sl];
        uint4 o;
        o.x = bfpack((float)(v.x & 0xffffu) * inv, (float)(v.x >> 16) * inv);
        o.y = bfpack((float)(v.y & 0xffffu) * inv, (float)(v.y >> 16) * inv);
        o.z = bfpack((float)(v.z & 0xffffu) * inv, (float)(v.z >> 16) * inv);
        o.w = bfpack((float)(v.w & 0xffffu) * inv, (float)(v.w >> 16) * inv);
        mfr[d][ksg] = __builtin_bit_cast(short8, o);
      }
  }
  __syncthreads();   // all count reads done -> Mlds reusable as W slots

  // ---- async-fill slots B,C (Wo[0], Wr[0]); barrier drains vmcnt -> ready ----
  w_stage(Wob, slotB);
  w_stage(Wrb, slotC);
  __syncthreads();

  // ---- layers: 2 barriers each ----
  for (int L = 0; L < LLd; ++L) {
    const bool more = (L < LLd - 1);
    f32x4 pre[8];
#pragma unroll
    for (int ct = 0; ct < 8; ++ct) pre[ct] = (f32x4){0.f, 0.f, 0.f, 0.f};

#pragma unroll
    for (int sg = 0; sg < 2; ++sg) {
      const unsigned* slot = (sg == 0) ? (const unsigned*)Wlds : (const unsigned*)slotB;
      // For each output fi-block kso: partial M-phase (2 f-tiles, 8 regs) ->
      // transpose -> main-phase kso. Only 8 accT regs live at any point.
#pragma unroll
      for (int kso = 0; kso < 4; ++kso) {
        f32x4 acc0 = (f32x4){0.f, 0.f, 0.f, 0.f};
        f32x4 acc1 = (f32x4){0.f, 0.f, 0.f, 0.f};
#pragma unroll
        for (int ksi = 0; ksi < 4; ++ksi) {
          short8 bfr = mfr[sg][ksi];
          short8 a0 = *(const short8*)&hTs[hchunk((2 * kso) * 16 + m, ksi * 4 + q)];
          acc0 = __builtin_amdgcn_mfma_f32_16x16x32_bf16(a0, bfr, acc0, 0, 0, 0);
          short8 a1 = *(const short8*)&hTs[hchunk((2 * kso + 1) * 16 + m, ksi * 4 + q)];
          acc1 = __builtin_amdgcn_mfma_f32_16x16x32_bf16(a1, bfr, acc1, 0, 0, 0);
        }
        // packed single-shfl transpose (identical math to r9, lo/hi = acc0/acc1)
        unsigned pk[4];
#pragma unroll
        for (int r = 0; r < 4; ++r) pk[r] = bfpack(acc0[r], acc1[r]);
        short8 afr;
#pragma unroll
        for (int j = 0; j < 8; ++j) {
          int srcl = ((((q & 1) << 1) + (j >> 2)) << 4) + m;
          unsigned v = (unsigned)__shfl((int)pk[j & 3], srcl, 64);
          afr[j] = (short)(unsigned short)((q >> 1) ? (v >> 16) : (v & 0xffffu));
        }
#pragma unroll
        for (int ct = 0; ct < 8; ++ct) {
          short8 bfr = wfrag(slot, ct, kso);
          pre[ct] = __builtin_amdgcn_mfma_f32_16x16x32_bf16(afr, bfr, pre[ct], 0, 0, 0);
        }
      }
    }
    // --- Wr segment: A-frags scalar-read from hTs, B from slot C ---
#pragma unroll
    for (int hf = 0; hf < 2; ++hf)
#pragma unroll
      for (int ksl = 0; ksl < 2; ++ksl) {
        const int ksg = hf * 2 + ksl;
        short8 afr;
#pragma unroll
        for (int j = 0; j < 8; ++j)
          afr[j] = (short)hTs[hidx(ksg * 32 + q * 8 + j, t0 + m)];
#pragma unroll
        for (int ct = 0; ct < 8; ++ct) {
          short8 bfr = wfrag(slotC, ct, ksg);
          pre[ct] = __builtin_amdgcn_mfma_f32_16x16x32_bf16(afr, bfr, pre[ct], 0, 0, 0);
        }
      }
    __syncthreads();   // bar1: all hTs + W-slot reads of this layer done
    if (more) {        // async restock, zero regs; lands under epilogue; bar2 drains
      w_stage(Wnb + (L + 1) * 16384, Wlds);
      w_stage(Wob + (L + 1) * 16384, slotB);
      w_stage(Wrb + (L + 1) * 16384, slotC);
    }
    // --- epilogue (register-diet): bias-mix folded into pre (one-shot), then
    //     in-place LN + ReLU. Peak ~= pre(32)+mfr(32)+gv/bv(16)+misc < 128. ---
    {
      float fiv[4], fov[4];
#pragma unroll
      for (int r = 0; r < 4; ++r) { fiv[r] = finS[t0 + q * 4 + r]; fov[r] = foutS[t0 + q * 4 + r]; }
#pragma unroll
      for (int ct2 = 0; ct2 < 8; ct2 += 4) {   // ct-halves: 4+4 transient bias regs
        float bn4[4], bo4[4];
#pragma unroll
        for (int cc = 0; cc < 4; ++cc) {
          int c = L * 128 + (ct2 + cc) * 16 + m;
          bn4[cc] = bn[c]; bo4[cc] = bo[c];
        }
#pragma unroll
        for (int cc = 0; cc < 4; ++cc)
#pragma unroll
          for (int r = 0; r < 4; ++r)
            pre[ct2 + cc][r] += fiv[r] * bn4[cc] + fov[r] * bo4[cc];
      }
      float gv[8], bv[8];
#pragma unroll
      for (int ct = 0; ct < 8; ++ct) {
        int c = L * 128 + ct * 16 + m;
        gv[ct] = lng[c]; bv[ct] = lnb[c];
      }
#pragma unroll
      for (int r = 0; r < 4; ++r) {
        const int tl = q * 4 + r;
        float sum = 0.f;
#pragma unroll
        for (int ct = 0; ct < 8; ++ct) sum += pre[ct][r];
        sum += __shfl_xor(sum, 1); sum += __shfl_xor(sum, 2);
        sum += __shfl_xor(sum, 4); sum += __shfl_xor(sum, 8);
        const float mu = sum * (1.0f / 128.0f);
        float sq = 0.f;
#pragma unroll
        for (int ct = 0; ct < 8; ++ct) { float d = pre[ct][r] - mu; sq += d * d; }
        sq += __shfl_xor(sq, 1); sq += __shfl_xor(sq, 2);
        sq += __shfl_xor(sq, 4); sq += __shfl_xor(sq, 8);
        const float rstd = rsqrtf(sq * (1.0f / 128.0f) + 1e-5f);
#pragma unroll
        for (int ct = 0; ct < 8; ++ct) {
          float o = fmaxf((pre[ct][r] - mu) * rstd * gv[ct] + bv[ct], 0.0f);
          hTs[hidx(ct * 16 + m, t0 + tl)] = f2bf(o);
        }
      }
    }
    __syncthreads();   // bar2: hTs visible + restock gloads drained (vmcnt 0)
  }

  // ---- pool: pooled[c][fo] = sum_t s[t][c]*h[t][fo]; wave w does fo-tile w ----
  f32x4 pl = (f32x4){0.f, 0.f, 0.f, 0.f};
#pragma unroll
  for (int ks = 0; ks < 4; ++ks) {
    short8 a = *(const short8*)&sTs[m * 136 + ks * 32 + q * 8];
    short8 b = *(const short8*)&hTs[hchunk(wave * 16 + m, ks * 4 + q)];
    pl = __builtin_amdgcn_mfma_f32_16x16x32_bf16(a, b, pl, 0, 0, 0);
  }
  float* pooledS = (float*)Mlds;   // W slots dead after last layer
#pragma unroll
  for (int r = 0; r < 4; ++r) pooledS[(q * 4 + r) * 132 + wave * 16 + m] = pl[r];
  __syncthreads();

  // ---- final LN + lin + mask (threads 0..255) ----
  if (tid < 256) {
    const int c = tid >> 4;
    const int j0 = (tid & 15) << 3;
    float v[8];
#pragma unroll
    for (int jj = 0; jj < 8; ++jj) v[jj] = pooledS[c * 132 + j0 + jj];
    float sum = 0.f;
#pragma unroll
    for (int jj = 0; jj < 8; ++jj) sum += v[jj];
#pragma unroll
    for (int mk = 1; mk < 16; mk <<= 1) sum += __shfl_xor(sum, mk, 64);
    float mu = sum * (1.0f / 128.0f);
    float sq = 0.f;
#pragma unroll
    for (int jj = 0; jj < 8; ++jj) { float d = v[jj] - mu; sq += d * d; }
#pragma unroll
    for (int mk = 1; mk < 16; mk <<= 1) sq += __shfl_xor(sq, mk, 64);
    float rstd = rsqrtf(sq * (1.0f / 128.0f) + 1e-5f);
    float dot = 0.f;
#pragma unroll
    for (int jj = 0; jj < 8; ++jj) {
      float nv = (v[jj] - mu) * rstd * flng[j0 + jj] + flnb[j0 + jj];
      dot += nv * linw[j0 + jj];
    }
#pragma unroll
    for (int mk = 1; mk < 16; mk <<= 1) dot += __shfl_xor(dot, mk, 64);
    if ((tid & 15) == 0) {
      float cm = (colsumS[c] > 0.f) ? 1.0f : 0.0f;
      float xcv = dot * cm;
      out[257 + g * CCd + c] = xcv;
      xcs[c] = xcv; axcs[c] = fabsf(xcv); msk[c] = cm;
    }
  }
  __syncthreads();
  if (tid == 0) {
    float so = 0.f, sa = 0.f, sd = 0.f;
#pragma unroll
    for (int k = 0; k < CCd; ++k) { so += xcs[k]; sa += axcs[k]; sd += msk[k] + 1e-7f; }
    out[g] = so + bias[0];
    l1g[g] = sa / sd;
  }
}

// ---------------- combine: losses = 0.01*reg + 0.01*mean_g(l1g) ----------------
__global__ __launch_bounds__(256) void combine_kernel(const float* __restrict__ l1g, const float* __restrict__ wsreg,
                                                      float* __restrict__ outp) {
  const int tid = threadIdx.x;
  float s2 = l1g[tid];
#pragma unroll
  for (int mk = 1; mk < 64; mk <<= 1) s2 += __shfl_xor(s2, mk, 64);
  __shared__ float rs2[4];
  if ((tid & 63) == 0) rs2[tid >> 6] = s2;
  __syncthreads();
  if (tid == 0) {
    float l1 = (rs2[0] + rs2[1] + rs2[2] + rs2[3]) * (1.0f / GG);
    outp[0] = 0.01f * wsreg[0] + 0.01f * l1;
  }
}

extern "C" void kernel_launch(void* const* d_in, const int* in_sizes, int n_in,
                              void* d_out, int out_size, void* d_ws, size_t ws_size,
                              hipStream_t stream) {
  (void)in_sizes; (void)n_in; (void)out_size; (void)ws_size;
  const float* x    = (const float*)d_in[0];
  const int*   ei   = (const int*)d_in[1];
  const int*   mask = (const int*)d_in[2];
  const float* s    = (const float*)d_in[3];
  const float* Wn   = (const float*)d_in[5];
  const float* bn   = (const float*)d_in[6];
  const float* Wo   = (const float*)d_in[7];
  const float* bo   = (const float*)d_in[8];
  const float* Wr   = (const float*)d_in[9];
  const float* lng  = (const float*)d_in[10];
  const float* lnb  = (const float*)d_in[11];
  const float* flng = (const float*)d_in[12];
  const float* flnb = (const float*)d_in[13];
  const float* linw = (const float*)d_in[14];
  const float* bias = (const float*)d_in[15];
  float* out = (float*)d_out;

  char* ws = (char*)d_ws;
  size_t off = 0;
  auto alloc = [&](size_t b) { char* p = ws + off; off += (b + 255) & ~(size_t)255; return p; };
  unsigned short* Wnb = (unsigned short*)alloc((size_t)LLd * HD * HD * 2);
  unsigned short* Wob = (unsigned short*)alloc((size_t)LLd * HD * HD * 2);
  unsigned short* Wrb = (unsigned short*)alloc((size_t)LLd * HD * HD * 2);
  float* l1g    = (float*)alloc((size_t)GG * 4);
  float* wsreg  = (float*)alloc(256);

  const int* srcA = ei;
  const int* tgtA = ei + EE;

  hipMemsetAsync(wsreg, 0, 4, stream);
  convert_w_kernel<<<LLd * HD * HD / (256 * 4), 256, 0, stream>>>(Wn, Wo, Wr, bo,
      (unsigned*)Wnb, (unsigned*)Wob, (unsigned*)Wrb, wsreg);
  fused_kernel<<<GG, 512, 0, stream>>>(x, srcA, tgtA, mask, Wnb, Wob, Wrb, bn, bo,
                                       lng, lnb, s, flng, flnb, linw, bias, out, l1g);
  combine_kernel<<<1, 256, 0, stream>>>(l1g, wsreg, out + 256);
}

// Round 12
// 138.749 us; speedup vs baseline: 1.4331x; 1.1582x over previous
//
#include <hip/hip_runtime.h>

#define NN   32768
#define HD   128
#define EE   524288
#define GG   256
#define EPG  2048
#define CCd  16
#define LLd  3

typedef short short8 __attribute__((ext_vector_type(8)));   // 8 bf16 = 4 VGPRs
typedef float f32x4 __attribute__((ext_vector_type(4)));

__device__ __forceinline__ unsigned short f2bf(float f) {
  unsigned u = __builtin_bit_cast(unsigned, f);
  return (unsigned short)((u + 0x7FFFu + ((u >> 16) & 1u)) >> 16);  // RNE
}
__device__ __forceinline__ unsigned bfpack(float a, float b) {
  return (unsigned)f2bf(a) | ((unsigned)f2bf(b) << 16);
}

// hTs layout: [f][t] bf16, stride 128 (no pad), 16-B chunks XOR-swizzled:
//   phys = (c&8) | ((c ^ f ^ (f>>3)) & 7),  c = t>>3
__device__ __forceinline__ int hchunk(int f, int c) {
  return f * 128 + (((c & 8) | ((c ^ f ^ (f >> 3)) & 7)) << 3);
}
__device__ __forceinline__ int hidx(int f, int t) {
  return hchunk(f, t >> 3) + (t & 7);
}

// ---------------- convert weights to bf16 + reg_loss accumulate ----------------
__global__ __launch_bounds__(256) void convert_w_kernel(const float* __restrict__ Wn, const float* __restrict__ Wo,
                                                        const float* __restrict__ Wr, const float* __restrict__ bo,
                                                        unsigned* __restrict__ Wnb, unsigned* __restrict__ Wob,
                                                        unsigned* __restrict__ Wrb, float* __restrict__ wsreg) {
  int i = blockIdx.x * 256 + threadIdx.x;   // 48 blocks; 4 floats per array per thread
  float4 a = *(const float4*)(Wn + (size_t)i * 4);
  float4 b = *(const float4*)(Wo + (size_t)i * 4);
  float4 c = *(const float4*)(Wr + (size_t)i * 4);
  *(uint2*)(Wnb + (size_t)i * 2) = make_uint2(bfpack(a.x, a.y), bfpack(a.z, a.w));
  *(uint2*)(Wob + (size_t)i * 2) = make_uint2(bfpack(b.x, b.y), bfpack(b.z, b.w));
  *(uint2*)(Wrb + (size_t)i * 2) = make_uint2(bfpack(c.x, c.y), bfpack(c.z, c.w));
  float s = fabsf(b.x) + fabsf(b.y) + fabsf(b.z) + fabsf(b.w);
  if (blockIdx.x == 0 && threadIdx.x < 96) {       // 384 bo elements
    float4 d = *(const float4*)(bo + threadIdx.x * 4);
    s += fabsf(d.x) + fabsf(d.y) + fabsf(d.z) + fabsf(d.w);
  }
#pragma unroll
  for (int mk = 1; mk < 64; mk <<= 1) s += __shfl_xor(s, mk, 64);
  if ((threadIdx.x & 63) == 0) atomicAdd(wsreg, s);
}

// ---------------- fully fused per-graph network ----------------
// grid 256 (1 block/graph), 512 threads (8 waves; wave w owns node rows [16w,16w+16)).
// REGISTER MODEL (r6-r11 conclusion): allocator envelope ~128 VGPRs; TWO persistent
// 32-reg arrays (pre + mfr) never fit -> M stays in LDS (r5's proven envelope,
// 120 VGPR no-spill). W staging via zero-register __builtin_amdgcn_global_load_lds
// through ONE rotating Wlds slot (swizzle pre-applied to per-lane GLOBAL source,
// m173; pair proven r9-r11). Schedule covers each W load: barA/issue Wo/M1-cover/
// barB/main1/barC/issue Wr/WrA-prefetch-cover/barD/Wr/barE/issue Wn'/epilogue/barF
// = 6 barriers/layer (r5 had 8 + w_store VALU + 16 prefetch regs).
__global__ __launch_bounds__(512) void fused_kernel(
    const float* __restrict__ x,
    const int* __restrict__ esrc, const int* __restrict__ etgt, const int* __restrict__ emask,
    const unsigned short* __restrict__ Wnb, const unsigned short* __restrict__ Wob,
    const unsigned short* __restrict__ Wrb,
    const float* __restrict__ bn, const float* __restrict__ bo,
    const float* __restrict__ lng, const float* __restrict__ lnb,
    const float* __restrict__ s,
    const float* __restrict__ flng, const float* __restrict__ flnb,
    const float* __restrict__ linw, const float* __restrict__ bias,
    float* __restrict__ out, float* __restrict__ l1g) {
  __shared__ __align__(16) unsigned short hTs[128 * 128];  // 32.0 KB  h^T, XOR-swizzled
  __shared__ __align__(16) unsigned short sTs[16 * 136];   //  4.3 KB  s^T [c][t]
  __shared__ __align__(16) unsigned Mlds[2 * 128 * 64];    // 64.0 KB  counts -> bf16 M (resident); pool scratch
  __shared__ __align__(16) unsigned Wlds[128 * 64];        // 32.0 KB  rotating W slot (bf16, swizzled)
  __shared__ float finS[128], foutS[128];
  __shared__ float colsumS[CCd], xcs[CCd], axcs[CCd], msk[CCd];

  const int g = blockIdx.x;
  const int tid = threadIdx.x;
  const int wave = tid >> 6;
  const int lane = tid & 63;
  const int m = lane & 15;
  const int q = lane >> 4;
  const int t0 = wave << 4;

  // ---- async W staging: global bf16 -> swizzled Wlds, ZERO VGPRs (r9-proven) ----
  auto w_stage = [&](const unsigned short* __restrict__ Wg) {
#pragma unroll
    for (int c = 0; c < 4; ++c) {
      int row = c * 32 + wave * 4 + (lane >> 4);
      int lc = (lane & 15) ^ (row & 7);
      const unsigned short* gp = Wg + row * 128 + lc * 8;   // 16 B = 8 bf16
      unsigned* lp = Wlds + c * 2048 + wave * 256;          // wave-uniform base
      __builtin_amdgcn_global_load_lds(
          (const __attribute__((address_space(1))) unsigned*)gp,
          (__attribute__((address_space(3))) unsigned*)lp, 16, 0, 0);
    }
  };
  // B-frag read from Wlds (swizzle matches w_stage; row&7 == m&7)
  auto wfrag = [&](int ct, int ksg) -> short8 {
    return *(const short8*)&Wlds[(ct * 16 + m) * 64 + (((ksg * 4 + q) ^ (m & 7)) << 2)];
  };

  // ---- entry: Wn[0] -> Wlds async; edge loads into regs (latency under phase 0) ----
  w_stage(Wnb);
  int et[4], es[4], em[4];
  {
    const int e0 = g * EPG;
#pragma unroll
    for (int i = 0; i < 4; ++i) {
      int e = e0 + i * 512 + tid;
      et[i] = etgt[e]; es[i] = esrc[e]; em[i] = emask[e];
    }
  }

  // ---- phase 0: zero counts + stage x->hTs (swizzled), s->sTs, colsum ----
  {
    uint4* cz = (uint4*)Mlds;   // 4096 uint4
#pragma unroll
    for (int i = 0; i < 8; ++i) cz[i * 512 + tid] = make_uint4(0u, 0u, 0u, 0u);

    const float4* xg = (const float4*)(x + (size_t)g * 16384);
#pragma unroll
    for (int i = 0; i < 8; ++i) {
      int flat = i * 512 + tid;           // 4096 float4s, fully coalesced
      int t = flat >> 5, f0 = (flat & 31) << 2;
      float4 v = xg[flat];
      hTs[hidx(f0 + 0, t)] = f2bf(v.x);
      hTs[hidx(f0 + 1, t)] = f2bf(v.y);
      hTs[hidx(f0 + 2, t)] = f2bf(v.z);
      hTs[hidx(f0 + 3, t)] = f2bf(v.w);
    }
    {
      int t = tid >> 2, c0 = (tid & 3) << 2;
      float4 v = *(const float4*)(s + (size_t)g * 2048 + t * 16 + c0);
      sTs[(c0 + 0) * 136 + t] = f2bf(v.x);
      sTs[(c0 + 1) * 136 + t] = f2bf(v.y);
      sTs[(c0 + 2) * 136 + t] = f2bf(v.z);
      sTs[(c0 + 3) * 136 + t] = f2bf(v.w);
    }
    if (tid < 64) {            // colsum: 4 lanes per column
      int c = tid & 15, qq = tid >> 4;
      float cs = 0.f;
      for (int tt = qq; tt < 128; tt += 4) cs += s[(size_t)g * 2048 + tt * 16 + c];
      cs += __shfl_xor(cs, 16); cs += __shfl_xor(cs, 32);
      if (qq == 0) colsumS[c] = cs;
    }
  }
  __syncthreads();

  // ---- phase 1: edge binning from prefetched regs, swizzled quads ----
  {
#pragma unroll
    for (int i = 0; i < 4; ++i) {
      int t = et[i] & 127;
      int sl = es[i] & 127;
      int dir = (em[i] != 0) ? 0 : 1;
      atomicAdd(&Mlds[dir * 8192 + t * 64 + (((sl >> 3) ^ (t & 7)) << 2) + ((sl >> 1) & 3)],
                1u << ((sl & 1) * 16));
    }
  }
  __syncthreads();

  // ---- phase 2: in-place count->bf16 (x inv-degree) + fin/fout (XOR slot order) ----
  {
    const int t = t0 + m;
    const int mm = m & 7;
    unsigned nin = 0, nout = 0;
#pragma unroll
    for (int k4 = 0; k4 < 4; ++k4) {
      int sl = (((q * 4 + k4) ^ mm) & 15) << 2;   // XOR-rotated phys slot order
      uint4 a = *(const uint4*)&Mlds[t * 64 + sl];
      uint4 b = *(const uint4*)&Mlds[8192 + t * 64 + sl];
      nin  += (a.x & 0xffffu) + (a.x >> 16) + (a.y & 0xffffu) + (a.y >> 16)
            + (a.z & 0xffffu) + (a.z >> 16) + (a.w & 0xffffu) + (a.w >> 16);
      nout += (b.x & 0xffffu) + (b.x >> 16) + (b.y & 0xffffu) + (b.y >> 16)
            + (b.z & 0xffffu) + (b.z >> 16) + (b.w & 0xffffu) + (b.w >> 16);
    }
    nin  += __shfl_xor((int)nin, 16);  nin  += __shfl_xor((int)nin, 32);
    nout += __shfl_xor((int)nout, 16); nout += __shfl_xor((int)nout, 32);
    unsigned dg = nin + nout;
    float inv = 1.0f / (float)(dg > 0 ? dg : 1);
    if (q == 0) { finS[t] = (float)nin * inv; foutS[t] = (float)nout * inv; }
#pragma unroll
    for (int d = 0; d < 2; ++d)
#pragma unroll
      for (int k4 = 0; k4 < 4; ++k4) {
        int sl = (((q * 4 + k4) ^ mm) & 15) << 2;
        unsigned* p = &Mlds[d * 8192 + t * 64 + sl];
        uint4 v = *(const uint4*)p;
        uint4 o;
        o.x = bfpack((float)(v.x & 0xffffu) * inv, (float)(v.x >> 16) * inv);
        o.y = bfpack((float)(v.y & 0xffffu) * inv, (float)(v.y >> 16) * inv);
        o.z = bfpack((float)(v.z & 0xffffu) * inv, (float)(v.z >> 16) * inv);
        o.w = bfpack((float)(v.w & 0xffffu) * inv, (float)(v.w >> 16) * inv);
        *(uint4*)p = o;
      }
  }
  __syncthreads();   // M resident in Mlds; Wn[0] drained into Wlds by this barrier

  // ---- layers: 6 barriers each, single rotating Wlds slot ----
  for (int L = 0; L < LLd; ++L) {
    const bool more = (L < LLd - 1);
    f32x4 pre[8];
#pragma unroll
    for (int ct = 0; ct < 8; ++ct) pre[ct] = (f32x4){0.f, 0.f, 0.f, 0.f};
    f32x4 accT[8];

    // === sg0: M-phase (B from Mlds dir0) + main (Wlds = Wn[L]) ===
#pragma unroll
    for (int ft = 0; ft < 8; ++ft) accT[ft] = (f32x4){0.f, 0.f, 0.f, 0.f};
#pragma unroll
    for (int ksg = 0; ksg < 4; ++ksg) {
      short8 bfr = *(const short8*)&Mlds[(t0 + m) * 64 + (((ksg * 4 + q) ^ (m & 7)) << 2)];
#pragma unroll
      for (int ft = 0; ft < 8; ++ft) {
        short8 afr = *(const short8*)&hTs[hchunk(ft * 16 + m, ksg * 4 + q)];
        accT[ft] = __builtin_amdgcn_mfma_f32_16x16x32_bf16(afr, bfr, accT[ft], 0, 0, 0);
      }
    }
#pragma unroll
    for (int ksg = 0; ksg < 4; ++ksg) {
      f32x4 lo = accT[2 * ksg], hi = accT[2 * ksg + 1];
      unsigned pk[4];
#pragma unroll
      for (int r = 0; r < 4; ++r) pk[r] = bfpack(lo[r], hi[r]);
      short8 afr;
#pragma unroll
      for (int j = 0; j < 8; ++j) {
        int srcl = ((((q & 1) << 1) + (j >> 2)) << 4) + m;
        unsigned v = (unsigned)__shfl((int)pk[j & 3], srcl, 64);
        afr[j] = (short)(unsigned short)((q >> 1) ? (v >> 16) : (v & 0xffffu));
      }
#pragma unroll
      for (int ct = 0; ct < 8; ++ct)
        pre[ct] = __builtin_amdgcn_mfma_f32_16x16x32_bf16(afr, wfrag(ct, ksg), pre[ct], 0, 0, 0);
    }
    __syncthreads();                       // barA: Wn reads done
    w_stage(Wob + L * 16384);              // issue Wo (async)

    // === sg1 M-phase covers the Wo load ===
#pragma unroll
    for (int ft = 0; ft < 8; ++ft) accT[ft] = (f32x4){0.f, 0.f, 0.f, 0.f};
#pragma unroll
    for (int ksg = 0; ksg < 4; ++ksg) {
      short8 bfr = *(const short8*)&Mlds[8192 + (t0 + m) * 64 + (((ksg * 4 + q) ^ (m & 7)) << 2)];
#pragma unroll
      for (int ft = 0; ft < 8; ++ft) {
        short8 afr = *(const short8*)&hTs[hchunk(ft * 16 + m, ksg * 4 + q)];
        accT[ft] = __builtin_amdgcn_mfma_f32_16x16x32_bf16(afr, bfr, accT[ft], 0, 0, 0);
      }
    }
    __syncthreads();                       // barB: Wo landed (vmcnt drained)
#pragma unroll
    for (int ksg = 0; ksg < 4; ++ksg) {
      f32x4 lo = accT[2 * ksg], hi = accT[2 * ksg + 1];
      unsigned pk[4];
#pragma unroll
      for (int r = 0; r < 4; ++r) pk[r] = bfpack(lo[r], hi[r]);
      short8 afr;
#pragma unroll
      for (int j = 0; j < 8; ++j) {
        int srcl = ((((q & 1) << 1) + (j >> 2)) << 4) + m;
        unsigned v = (unsigned)__shfl((int)pk[j & 3], srcl, 64);
        afr[j] = (short)(unsigned short)((q >> 1) ? (v >> 16) : (v & 0xffffu));
      }
#pragma unroll
      for (int ct = 0; ct < 8; ++ct)
        pre[ct] = __builtin_amdgcn_mfma_f32_16x16x32_bf16(afr, wfrag(ct, ksg), pre[ct], 0, 0, 0);
    }
    __syncthreads();                       // barC: Wo reads done
    w_stage(Wrb + L * 16384);              // issue Wr (async)
    // prefetch Wr A-frags from hTs (cover; accT dead -> 16 fresh regs)
    short8 wra0, wra1, wra2, wra3;
    {
#pragma unroll
      for (int j = 0; j < 8; ++j) {
        wra0[j] = (short)hTs[hidx(0 * 32 + q * 8 + j, t0 + m)];
        wra1[j] = (short)hTs[hidx(1 * 32 + q * 8 + j, t0 + m)];
        wra2[j] = (short)hTs[hidx(2 * 32 + q * 8 + j, t0 + m)];
        wra3[j] = (short)hTs[hidx(3 * 32 + q * 8 + j, t0 + m)];
      }
    }
    __syncthreads();                       // barD: Wr landed
#pragma unroll
    for (int ct = 0; ct < 8; ++ct) {
      pre[ct] = __builtin_amdgcn_mfma_f32_16x16x32_bf16(wra0, wfrag(ct, 0), pre[ct], 0, 0, 0);
      pre[ct] = __builtin_amdgcn_mfma_f32_16x16x32_bf16(wra1, wfrag(ct, 1), pre[ct], 0, 0, 0);
      pre[ct] = __builtin_amdgcn_mfma_f32_16x16x32_bf16(wra2, wfrag(ct, 2), pre[ct], 0, 0, 0);
      pre[ct] = __builtin_amdgcn_mfma_f32_16x16x32_bf16(wra3, wfrag(ct, 3), pre[ct], 0, 0, 0);
    }
    __syncthreads();                       // barE: Wr + hTs reads done
    if (more) w_stage(Wnb + (L + 1) * 16384);   // issue Wn[L+1]; epilogue covers

    // --- epilogue (register-diet, r11): bias-mix folded into pre, in-place LN ---
    {
      float fiv[4], fov[4];
#pragma unroll
      for (int r = 0; r < 4; ++r) { fiv[r] = finS[t0 + q * 4 + r]; fov[r] = foutS[t0 + q * 4 + r]; }
#pragma unroll
      for (int ct2 = 0; ct2 < 8; ct2 += 4) {   // ct-halves: 4+4 transient bias regs
        float bn4[4], bo4[4];
#pragma unroll
        for (int cc = 0; cc < 4; ++cc) {
          int c = L * 128 + (ct2 + cc) * 16 + m;
          bn4[cc] = bn[c]; bo4[cc] = bo[c];
        }
#pragma unroll
        for (int cc = 0; cc < 4; ++cc)
#pragma unroll
          for (int r = 0; r < 4; ++r)
            pre[ct2 + cc][r] += fiv[r] * bn4[cc] + fov[r] * bo4[cc];
      }
      float gv[8], bv[8];
#pragma unroll
      for (int ct = 0; ct < 8; ++ct) {
        int c = L * 128 + ct * 16 + m;
        gv[ct] = lng[c]; bv[ct] = lnb[c];
      }
#pragma unroll
      for (int r = 0; r < 4; ++r) {
        const int tl = q * 4 + r;
        float sum = 0.f;
#pragma unroll
        for (int ct = 0; ct < 8; ++ct) sum += pre[ct][r];
        sum += __shfl_xor(sum, 1); sum += __shfl_xor(sum, 2);
        sum += __shfl_xor(sum, 4); sum += __shfl_xor(sum, 8);
        const float mu = sum * (1.0f / 128.0f);
        float sq = 0.f;
#pragma unroll
        for (int ct = 0; ct < 8; ++ct) { float d = pre[ct][r] - mu; sq += d * d; }
        sq += __shfl_xor(sq, 1); sq += __shfl_xor(sq, 2);
        sq += __shfl_xor(sq, 4); sq += __shfl_xor(sq, 8);
        const float rstd = rsqrtf(sq * (1.0f / 128.0f) + 1e-5f);
#pragma unroll
        for (int ct = 0; ct < 8; ++ct) {
          float o = fmaxf((pre[ct][r] - mu) * rstd * gv[ct] + bv[ct], 0.0f);
          hTs[hidx(ct * 16 + m, t0 + tl)] = f2bf(o);
        }
      }
    }
    __syncthreads();                       // barF: hTs visible + Wn[L+1] drained
  }

  // ---- pool: pooled[c][fo] = sum_t s[t][c]*h[t][fo]; wave w does fo-tile w ----
  f32x4 pl = (f32x4){0.f, 0.f, 0.f, 0.f};
#pragma unroll
  for (int ks = 0; ks < 4; ++ks) {
    short8 a = *(const short8*)&sTs[m * 136 + ks * 32 + q * 8];
    short8 b = *(const short8*)&hTs[hchunk(wave * 16 + m, ks * 4 + q)];
    pl = __builtin_amdgcn_mfma_f32_16x16x32_bf16(a, b, pl, 0, 0, 0);
  }
  float* pooledS = (float*)Mlds;   // M dead after last layer's M-phases
#pragma unroll
  for (int r = 0; r < 4; ++r) pooledS[(q * 4 + r) * 132 + wave * 16 + m] = pl[r];
  __syncthreads();

  // ---- final LN + lin + mask (threads 0..255) ----
  if (tid < 256) {
    const int c = tid >> 4;
    const int j0 = (tid & 15) << 3;
    float v[8];
#pragma unroll
    for (int jj = 0; jj < 8; ++jj) v[jj] = pooledS[c * 132 + j0 + jj];
    float sum = 0.f;
#pragma unroll
    for (int jj = 0; jj < 8; ++jj) sum += v[jj];
#pragma unroll
    for (int mk = 1; mk < 16; mk <<= 1) sum += __shfl_xor(sum, mk, 64);
    float mu = sum * (1.0f / 128.0f);
    float sq = 0.f;
#pragma unroll
    for (int jj = 0; jj < 8; ++jj) { float d = v[jj] - mu; sq += d * d; }
#pragma unroll
    for (int mk = 1; mk < 16; mk <<= 1) sq += __shfl_xor(sq, mk, 64);
    float rstd = rsqrtf(sq * (1.0f / 128.0f) + 1e-5f);
    float dot = 0.f;
#pragma unroll
    for (int jj = 0; jj < 8; ++jj) {
      float nv = (v[jj] - mu) * rstd * flng[j0 + jj] + flnb[j0 + jj];
      dot += nv * linw[j0 + jj];
    }
#pragma unroll
    for (int mk = 1; mk < 16; mk <<= 1) dot += __shfl_xor(dot, mk, 64);
    if ((tid & 15) == 0) {
      float cm = (colsumS[c] > 0.f) ? 1.0f : 0.0f;
      float xcv = dot * cm;
      out[257 + g * CCd + c] = xcv;
      xcs[c] = xcv; axcs[c] = fabsf(xcv); msk[c] = cm;
    }
  }
  __syncthreads();
  if (tid == 0) {
    float so = 0.f, sa = 0.f, sd = 0.f;
#pragma unroll
    for (int k = 0; k < CCd; ++k) { so += xcs[k]; sa += axcs[k]; sd += msk[k] + 1e-7f; }
    out[g] = so + bias[0];
    l1g[g] = sa / sd;
  }
}

// ---------------- combine: losses = 0.01*reg + 0.01*mean_g(l1g) ----------------
__global__ __launch_bounds__(256) void combine_kernel(const float* __restrict__ l1g, const float* __restrict__ wsreg,
                                                      float* __restrict__ outp) {
  const int tid = threadIdx.x;
  float s2 = l1g[tid];
#pragma unroll
  for (int mk = 1; mk < 64; mk <<= 1) s2 += __shfl_xor(s2, mk, 64);
  __shared__ float rs2[4];
  if ((tid & 63) == 0) rs2[tid >> 6] = s2;
  __syncthreads();
  if (tid == 0) {
    float l1 = (rs2[0] + rs2[1] + rs2[2] + rs2[3]) * (1.0f / GG);
    outp[0] = 0.01f * wsreg[0] + 0.01f * l1;
  }
}

extern "C" void kernel_launch(void* const* d_in, const int* in_sizes, int n_in,
                              void* d_out, int out_size, void* d_ws, size_t ws_size,
                              hipStream_t stream) {
  (void)in_sizes; (void)n_in; (void)out_size; (void)ws_size;
  const float* x    = (const float*)d_in[0];
  const int*   ei   = (const int*)d_in[1];
  const int*   mask = (const int*)d_in[2];
  const float* s    = (const float*)d_in[3];
  const float* Wn   = (const float*)d_in[5];
  const float* bn   = (const float*)d_in[6];
  const float* Wo   = (const float*)d_in[7];
  const float* bo   = (const float*)d_in[8];
  const float* Wr   = (const float*)d_in[9];
  const float* lng  = (const float*)d_in[10];
  const float* lnb  = (const float*)d_in[11];
  const float* flng = (const float*)d_in[12];
  const float* flnb = (const float*)d_in[13];
  const float* linw = (const float*)d_in[14];
  const float* bias = (const float*)d_in[15];
  float* out = (float*)d_out;

  char* ws = (char*)d_ws;
  size_t off = 0;
  auto alloc = [&](size_t b) { char* p = ws + off; off += (b + 255) & ~(size_t)255; return p; };
  unsigned short* Wnb = (unsigned short*)alloc((size_t)LLd * HD * HD * 2);
  unsigned short* Wob = (unsigned short*)alloc((size_t)LLd * HD * HD * 2);
  unsigned short* Wrb = (unsigned short*)alloc((size_t)LLd * HD * HD * 2);
  float* l1g    = (float*)alloc((size_t)GG * 4);
  float* wsreg  = (float*)alloc(256);

  const int* srcA = ei;
  const int* tgtA = ei + EE;

  hipMemsetAsync(wsreg, 0, 4, stream);
  convert_w_kernel<<<LLd * HD * HD / (256 * 4), 256, 0, stream>>>(Wn, Wo, Wr, bo,
      (unsigned*)Wnb, (unsigned*)Wob, (unsigned*)Wrb, wsreg);
  fused_kernel<<<GG, 512, 0, stream>>>(x, srcA, tgtA, mask, Wnb, Wob, Wrb, bn, bo,
                                       lng, lnb, s, flng, flnb, linw, bias, out, l1g);
  combine_kernel<<<1, 256, 0, stream>>>(l1g, wsreg, out + 256);
}

// Round 13
// 134.225 us; speedup vs baseline: 1.4814x; 1.0337x over previous
//
#include <hip/hip_runtime.h>

#define NN   32768
#define HD   128
#define EE   524288
#define GG   256
#define EPG  2048
#define CCd  16
#define LLd  3

typedef short short8 __attribute__((ext_vector_type(8)));   // 8 bf16 = 4 VGPRs
typedef float f32x4 __attribute__((ext_vector_type(4)));

__device__ __forceinline__ unsigned short f2bf(float f) {
  unsigned u = __builtin_bit_cast(unsigned, f);
  return (unsigned short)((u + 0x7FFFu + ((u >> 16) & 1u)) >> 16);  // RNE
}
__device__ __forceinline__ unsigned bfpack(float a, float b) {
  return (unsigned)f2bf(a) | ((unsigned)f2bf(b) << 16);
}

// hTs layout: [f][t] bf16, stride 128, 16-B chunks XOR-swizzled with a FULL 4-bit
// key: phys = (c ^ s(f)) & 15, s(f) = (f ^ (f>>2)) & 15 (bijective in f&15).
// Row stride == 0 mod banks, so ONLY the chunk swizzle decorrelates banks; a
// 3-bit key (r5-r12) spanned 8 quads -> 8 lanes/quad on b128 reads (~2.9x);
// 4-bit spans all 16 -> even 4/quad (b128 floor). [r12 counter audit]
__device__ __forceinline__ int hchunk(int f, int c) {
  return f * 128 + (((c ^ ((f ^ (f >> 2)) & 15)) & 15) << 3);
}
__device__ __forceinline__ int hidx(int f, int t) {
  return hchunk(f, t >> 3) + (t & 7);
}

// ---------------- convert weights to bf16 + reg_loss accumulate ----------------
__global__ __launch_bounds__(256) void convert_w_kernel(const float* __restrict__ Wn, const float* __restrict__ Wo,
                                                        const float* __restrict__ Wr, const float* __restrict__ bo,
                                                        unsigned* __restrict__ Wnb, unsigned* __restrict__ Wob,
                                                        unsigned* __restrict__ Wrb, float* __restrict__ wsreg) {
  int i = blockIdx.x * 256 + threadIdx.x;   // 48 blocks; 4 floats per array per thread
  float4 a = *(const float4*)(Wn + (size_t)i * 4);
  float4 b = *(const float4*)(Wo + (size_t)i * 4);
  float4 c = *(const float4*)(Wr + (size_t)i * 4);
  *(uint2*)(Wnb + (size_t)i * 2) = make_uint2(bfpack(a.x, a.y), bfpack(a.z, a.w));
  *(uint2*)(Wob + (size_t)i * 2) = make_uint2(bfpack(b.x, b.y), bfpack(b.z, b.w));
  *(uint2*)(Wrb + (size_t)i * 2) = make_uint2(bfpack(c.x, c.y), bfpack(c.z, c.w));
  float s = fabsf(b.x) + fabsf(b.y) + fabsf(b.z) + fabsf(b.w);
  if (blockIdx.x == 0 && threadIdx.x < 96) {       // 384 bo elements
    float4 d = *(const float4*)(bo + threadIdx.x * 4);
    s += fabsf(d.x) + fabsf(d.y) + fabsf(d.z) + fabsf(d.w);
  }
#pragma unroll
  for (int mk = 1; mk < 64; mk <<= 1) s += __shfl_xor(s, mk, 64);
  if ((threadIdx.x & 63) == 0) atomicAdd(wsreg, s);
}

// ---------------- fully fused per-graph network ----------------
// grid 256 (1 block/graph), 512 threads (8 waves; wave w owns node rows [16w,16w+16)).
// r12 structure (proven, no spills): M resident in LDS, W via zero-register
// global_load_lds through one rotating Wlds slot (swizzle pre-applied to per-lane
// GLOBAL source), 6 barriers/layer, r11 epilogue diet. r13 delta: ALL LDS chunk
// swizzles widened 3-bit -> 4-bit XOR keys (see hchunk comment) to cut the
// 8-lanes/bank-quad b128 conflicts that were ~21% of kernel time.
__global__ __launch_bounds__(512) void fused_kernel(
    const float* __restrict__ x,
    const int* __restrict__ esrc, const int* __restrict__ etgt, const int* __restrict__ emask,
    const unsigned short* __restrict__ Wnb, const unsigned short* __restrict__ Wob,
    const unsigned short* __restrict__ Wrb,
    const float* __restrict__ bn, const float* __restrict__ bo,
    const float* __restrict__ lng, const float* __restrict__ lnb,
    const float* __restrict__ s,
    const float* __restrict__ flng, const float* __restrict__ flnb,
    const float* __restrict__ linw, const float* __restrict__ bias,
    float* __restrict__ out, float* __restrict__ l1g) {
  __shared__ __align__(16) unsigned short hTs[128 * 128];  // 32.0 KB  h^T, XOR-swizzled
  __shared__ __align__(16) unsigned short sTs[16 * 136];   //  4.3 KB  s^T [c][t]
  __shared__ __align__(16) unsigned Mlds[2 * 128 * 64];    // 64.0 KB  counts -> bf16 M (resident); pool scratch
  __shared__ __align__(16) unsigned Wlds[128 * 64];        // 32.0 KB  rotating W slot (bf16, swizzled)
  __shared__ float finS[128], foutS[128];
  __shared__ float colsumS[CCd], xcs[CCd], axcs[CCd], msk[CCd];

  const int g = blockIdx.x;
  const int tid = threadIdx.x;
  const int wave = tid >> 6;
  const int lane = tid & 63;
  const int m = lane & 15;
  const int q = lane >> 4;
  const int t0 = wave << 4;

  // ---- async W staging: global bf16 -> swizzled Wlds, ZERO VGPRs (r9-proven) ----
  // LDS dest linear in lane order (HW constraint); phys chunk (lane&15) of row r
  // receives logical chunk (lane&15)^(r&15) -> read phys = logical^(r&15).
  auto w_stage = [&](const unsigned short* __restrict__ Wg) {
#pragma unroll
    for (int c = 0; c < 4; ++c) {
      int row = c * 32 + wave * 4 + (lane >> 4);
      int lc = (lane & 15) ^ (row & 15);
      const unsigned short* gp = Wg + row * 128 + lc * 8;   // 16 B = 8 bf16
      unsigned* lp = Wlds + c * 2048 + wave * 256;          // wave-uniform base
      __builtin_amdgcn_global_load_lds(
          (const __attribute__((address_space(1))) unsigned*)gp,
          (__attribute__((address_space(3))) unsigned*)lp, 16, 0, 0);
    }
  };
  // B-frag read from Wlds (row = ct*16+m -> row&15 == m)
  auto wfrag = [&](int ct, int ksg) -> short8 {
    return *(const short8*)&Wlds[(ct * 16 + m) * 64 + ((((ksg * 4 + q) ^ m) & 15) << 2)];
  };

  // ---- entry: Wn[0] -> Wlds async; edge loads into regs (latency under phase 0) ----
  w_stage(Wnb);
  int et[4], es[4], em[4];
  {
    const int e0 = g * EPG;
#pragma unroll
    for (int i = 0; i < 4; ++i) {
      int e = e0 + i * 512 + tid;
      et[i] = etgt[e]; es[i] = esrc[e]; em[i] = emask[e];
    }
  }

  // ---- phase 0: zero counts + stage x->hTs (swizzled), s->sTs, colsum ----
  {
    uint4* cz = (uint4*)Mlds;   // 4096 uint4
#pragma unroll
    for (int i = 0; i < 8; ++i) cz[i * 512 + tid] = make_uint4(0u, 0u, 0u, 0u);

    const float4* xg = (const float4*)(x + (size_t)g * 16384);
#pragma unroll
    for (int i = 0; i < 8; ++i) {
      int flat = i * 512 + tid;           // 4096 float4s, fully coalesced
      int t = flat >> 5, f0 = (flat & 31) << 2;
      float4 v = xg[flat];
      hTs[hidx(f0 + 0, t)] = f2bf(v.x);
      hTs[hidx(f0 + 1, t)] = f2bf(v.y);
      hTs[hidx(f0 + 2, t)] = f2bf(v.z);
      hTs[hidx(f0 + 3, t)] = f2bf(v.w);
    }
    {
      int t = tid >> 2, c0 = (tid & 3) << 2;
      float4 v = *(const float4*)(s + (size_t)g * 2048 + t * 16 + c0);
      sTs[(c0 + 0) * 136 + t] = f2bf(v.x);
      sTs[(c0 + 1) * 136 + t] = f2bf(v.y);
      sTs[(c0 + 2) * 136 + t] = f2bf(v.z);
      sTs[(c0 + 3) * 136 + t] = f2bf(v.w);
    }
    if (tid < 64) {            // colsum: 4 lanes per column
      int c = tid & 15, qq = tid >> 4;
      float cs = 0.f;
      for (int tt = qq; tt < 128; tt += 4) cs += s[(size_t)g * 2048 + tt * 16 + c];
      cs += __shfl_xor(cs, 16); cs += __shfl_xor(cs, 32);
      if (qq == 0) colsumS[c] = cs;
    }
  }
  __syncthreads();

  // ---- phase 1: edge binning from prefetched regs, 4-bit-swizzled chunks ----
  {
#pragma unroll
    for (int i = 0; i < 4; ++i) {
      int t = et[i] & 127;
      int sl = es[i] & 127;
      int dir = (em[i] != 0) ? 0 : 1;
      atomicAdd(&Mlds[dir * 8192 + t * 64 + ((((sl >> 3) ^ (t & 15)) & 15) << 2) + ((sl >> 1) & 3)],
                1u << ((sl & 1) * 16));
    }
  }
  __syncthreads();

  // ---- phase 2: in-place count->bf16 (x inv-degree) + fin/fout (t&15 == m) ----
  {
    const int t = t0 + m;
    unsigned nin = 0, nout = 0;
#pragma unroll
    for (int k4 = 0; k4 < 4; ++k4) {
      int sl = (((q * 4 + k4) ^ m) & 15) << 2;   // XOR-rotated phys slot order
      uint4 a = *(const uint4*)&Mlds[t * 64 + sl];
      uint4 b = *(const uint4*)&Mlds[8192 + t * 64 + sl];
      nin  += (a.x & 0xffffu) + (a.x >> 16) + (a.y & 0xffffu) + (a.y >> 16)
            + (a.z & 0xffffu) + (a.z >> 16) + (a.w & 0xffffu) + (a.w >> 16);
      nout += (b.x & 0xffffu) + (b.x >> 16) + (b.y & 0xffffu) + (b.y >> 16)
            + (b.z & 0xffffu) + (b.z >> 16) + (b.w & 0xffffu) + (b.w >> 16);
    }
    nin  += __shfl_xor((int)nin, 16);  nin  += __shfl_xor((int)nin, 32);
    nout += __shfl_xor((int)nout, 16); nout += __shfl_xor((int)nout, 32);
    unsigned dg = nin + nout;
    float inv = 1.0f / (float)(dg > 0 ? dg : 1);
    if (q == 0) { finS[t] = (float)nin * inv; foutS[t] = (float)nout * inv; }
#pragma unroll
    for (int d = 0; d < 2; ++d)
#pragma unroll
      for (int k4 = 0; k4 < 4; ++k4) {
        int sl = (((q * 4 + k4) ^ m) & 15) << 2;
        unsigned* p = &Mlds[d * 8192 + t * 64 + sl];
        uint4 v = *(const uint4*)p;
        uint4 o;
        o.x = bfpack((float)(v.x & 0xffffu) * inv, (float)(v.x >> 16) * inv);
        o.y = bfpack((float)(v.y & 0xffffu) * inv, (float)(v.y >> 16) * inv);
        o.z = bfpack((float)(v.z & 0xffffu) * inv, (float)(v.z >> 16) * inv);
        o.w = bfpack((float)(v.w & 0xffffu) * inv, (float)(v.w >> 16) * inv);
        *(uint4*)p = o;
      }
  }
  __syncthreads();   // M resident in Mlds; Wn[0] drained into Wlds by this barrier

  // ---- layers: 6 barriers each, single rotating Wlds slot ----
  for (int L = 0; L < LLd; ++L) {
    const bool more = (L < LLd - 1);
    f32x4 pre[8];
#pragma unroll
    for (int ct = 0; ct < 8; ++ct) pre[ct] = (f32x4){0.f, 0.f, 0.f, 0.f};
    f32x4 accT[8];

    // === sg0: M-phase (B from Mlds dir0) + main (Wlds = Wn[L]) ===
#pragma unroll
    for (int ft = 0; ft < 8; ++ft) accT[ft] = (f32x4){0.f, 0.f, 0.f, 0.f};
#pragma unroll
    for (int ksg = 0; ksg < 4; ++ksg) {
      short8 bfr = *(const short8*)&Mlds[(t0 + m) * 64 + ((((ksg * 4 + q) ^ m) & 15) << 2)];
#pragma unroll
      for (int ft = 0; ft < 8; ++ft) {
        short8 afr = *(const short8*)&hTs[hchunk(ft * 16 + m, ksg * 4 + q)];
        accT[ft] = __builtin_amdgcn_mfma_f32_16x16x32_bf16(afr, bfr, accT[ft], 0, 0, 0);
      }
    }
#pragma unroll
    for (int ksg = 0; ksg < 4; ++ksg) {
      f32x4 lo = accT[2 * ksg], hi = accT[2 * ksg + 1];
      unsigned pk[4];
#pragma unroll
      for (int r = 0; r < 4; ++r) pk[r] = bfpack(lo[r], hi[r]);
      short8 afr;
#pragma unroll
      for (int j = 0; j < 8; ++j) {
        int srcl = ((((q & 1) << 1) + (j >> 2)) << 4) + m;
        unsigned v = (unsigned)__shfl((int)pk[j & 3], srcl, 64);
        afr[j] = (short)(unsigned short)((q >> 1) ? (v >> 16) : (v & 0xffffu));
      }
#pragma unroll
      for (int ct = 0; ct < 8; ++ct)
        pre[ct] = __builtin_amdgcn_mfma_f32_16x16x32_bf16(afr, wfrag(ct, ksg), pre[ct], 0, 0, 0);
    }
    __syncthreads();                       // barA: Wn reads done
    w_stage(Wob + L * 16384);              // issue Wo (async)

    // === sg1 M-phase covers the Wo load ===
#pragma unroll
    for (int ft = 0; ft < 8; ++ft) accT[ft] = (f32x4){0.f, 0.f, 0.f, 0.f};
#pragma unroll
    for (int ksg = 0; ksg < 4; ++ksg) {
      short8 bfr = *(const short8*)&Mlds[8192 + (t0 + m) * 64 + ((((ksg * 4 + q) ^ m) & 15) << 2)];
#pragma unroll
      for (int ft = 0; ft < 8; ++ft) {
        short8 afr = *(const short8*)&hTs[hchunk(ft * 16 + m, ksg * 4 + q)];
        accT[ft] = __builtin_amdgcn_mfma_f32_16x16x32_bf16(afr, bfr, accT[ft], 0, 0, 0);
      }
    }
    __syncthreads();                       // barB: Wo landed (vmcnt drained)
#pragma unroll
    for (int ksg = 0; ksg < 4; ++ksg) {
      f32x4 lo = accT[2 * ksg], hi = accT[2 * ksg + 1];
      unsigned pk[4];
#pragma unroll
      for (int r = 0; r < 4; ++r) pk[r] = bfpack(lo[r], hi[r]);
      short8 afr;
#pragma unroll
      for (int j = 0; j < 8; ++j) {
        int srcl = ((((q & 1) << 1) + (j >> 2)) << 4) + m;
        unsigned v = (unsigned)__shfl((int)pk[j & 3], srcl, 64);
        afr[j] = (short)(unsigned short)((q >> 1) ? (v >> 16) : (v & 0xffffu));
      }
#pragma unroll
      for (int ct = 0; ct < 8; ++ct)
        pre[ct] = __builtin_amdgcn_mfma_f32_16x16x32_bf16(afr, wfrag(ct, ksg), pre[ct], 0, 0, 0);
    }
    __syncthreads();                       // barC: Wo reads done
    w_stage(Wrb + L * 16384);              // issue Wr (async)
    // prefetch Wr A-frags from hTs (cover; accT dead -> 16 fresh regs)
    short8 wra0, wra1, wra2, wra3;
    {
#pragma unroll
      for (int j = 0; j < 8; ++j) {
        wra0[j] = (short)hTs[hidx(0 * 32 + q * 8 + j, t0 + m)];
        wra1[j] = (short)hTs[hidx(1 * 32 + q * 8 + j, t0 + m)];
        wra2[j] = (short)hTs[hidx(2 * 32 + q * 8 + j, t0 + m)];
        wra3[j] = (short)hTs[hidx(3 * 32 + q * 8 + j, t0 + m)];
      }
    }
    __syncthreads();                       // barD: Wr landed
#pragma unroll
    for (int ct = 0; ct < 8; ++ct) {
      pre[ct] = __builtin_amdgcn_mfma_f32_16x16x32_bf16(wra0, wfrag(ct, 0), pre[ct], 0, 0, 0);
      pre[ct] = __builtin_amdgcn_mfma_f32_16x16x32_bf16(wra1, wfrag(ct, 1), pre[ct], 0, 0, 0);
      pre[ct] = __builtin_amdgcn_mfma_f32_16x16x32_bf16(wra2, wfrag(ct, 2), pre[ct], 0, 0, 0);
      pre[ct] = __builtin_amdgcn_mfma_f32_16x16x32_bf16(wra3, wfrag(ct, 3), pre[ct], 0, 0, 0);
    }
    __syncthreads();                       // barE: Wr + hTs reads done
    if (more) w_stage(Wnb + (L + 1) * 16384);   // issue Wn[L+1]; epilogue covers

    // --- epilogue (register-diet, r11): bias-mix folded into pre, in-place LN ---
    {
      float fiv[4], fov[4];
#pragma unroll
      for (int r = 0; r < 4; ++r) { fiv[r] = finS[t0 + q * 4 + r]; fov[r] = foutS[t0 + q * 4 + r]; }
#pragma unroll
      for (int ct2 = 0; ct2 < 8; ct2 += 4) {   // ct-halves: 4+4 transient bias regs
        float bn4[4], bo4[4];
#pragma unroll
        for (int cc = 0; cc < 4; ++cc) {
          int c = L * 128 + (ct2 + cc) * 16 + m;
          bn4[cc] = bn[c]; bo4[cc] = bo[c];
        }
#pragma unroll
        for (int cc = 0; cc < 4; ++cc)
#pragma unroll
          for (int r = 0; r < 4; ++r)
            pre[ct2 + cc][r] += fiv[r] * bn4[cc] + fov[r] * bo4[cc];
      }
      float gv[8], bv[8];
#pragma unroll
      for (int ct = 0; ct < 8; ++ct) {
        int c = L * 128 + ct * 16 + m;
        gv[ct] = lng[c]; bv[ct] = lnb[c];
      }
#pragma unroll
      for (int r = 0; r < 4; ++r) {
        const int tl = q * 4 + r;
        float sum = 0.f;
#pragma unroll
        for (int ct = 0; ct < 8; ++ct) sum += pre[ct][r];
        sum += __shfl_xor(sum, 1); sum += __shfl_xor(sum, 2);
        sum += __shfl_xor(sum, 4); sum += __shfl_xor(sum, 8);
        const float mu = sum * (1.0f / 128.0f);
        float sq = 0.f;
#pragma unroll
        for (int ct = 0; ct < 8; ++ct) { float d = pre[ct][r] - mu; sq += d * d; }
        sq += __shfl_xor(sq, 1); sq += __shfl_xor(sq, 2);
        sq += __shfl_xor(sq, 4); sq += __shfl_xor(sq, 8);
        const float rstd = rsqrtf(sq * (1.0f / 128.0f) + 1e-5f);
#pragma unroll
        for (int ct = 0; ct < 8; ++ct) {
          float o = fmaxf((pre[ct][r] - mu) * rstd * gv[ct] + bv[ct], 0.0f);
          hTs[hidx(ct * 16 + m, t0 + tl)] = f2bf(o);
        }
      }
    }
    __syncthreads();                       // barF: hTs visible + Wn[L+1] drained
  }

  // ---- pool: pooled[c][fo] = sum_t s[t][c]*h[t][fo]; wave w does fo-tile w ----
  f32x4 pl = (f32x4){0.f, 0.f, 0.f, 0.f};
#pragma unroll
  for (int ks = 0; ks < 4; ++ks) {
    short8 a = *(const short8*)&sTs[m * 136 + ks * 32 + q * 8];
    short8 b = *(const short8*)&hTs[hchunk(wave * 16 + m, ks * 4 + q)];
    pl = __builtin_amdgcn_mfma_f32_16x16x32_bf16(a, b, pl, 0, 0, 0);
  }
  float* pooledS = (float*)Mlds;   // M dead after last layer's M-phases
#pragma unroll
  for (int r = 0; r < 4; ++r) pooledS[(q * 4 + r) * 132 + wave * 16 + m] = pl[r];
  __syncthreads();

  // ---- final LN + lin + mask (threads 0..255) ----
  if (tid < 256) {
    const int c = tid >> 4;
    const int j0 = (tid & 15) << 3;
    float v[8];
#pragma unroll
    for (int jj = 0; jj < 8; ++jj) v[jj] = pooledS[c * 132 + j0 + jj];
    float sum = 0.f;
#pragma unroll
    for (int jj = 0; jj < 8; ++jj) sum += v[jj];
#pragma unroll
    for (int mk = 1; mk < 16; mk <<= 1) sum += __shfl_xor(sum, mk, 64);
    float mu = sum * (1.0f / 128.0f);
    float sq = 0.f;
#pragma unroll
    for (int jj = 0; jj < 8; ++jj) { float d = v[jj] - mu; sq += d * d; }
#pragma unroll
    for (int mk = 1; mk < 16; mk <<= 1) sq += __shfl_xor(sq, mk, 64);
    float rstd = rsqrtf(sq * (1.0f / 128.0f) + 1e-5f);
    float dot = 0.f;
#pragma unroll
    for (int jj = 0; jj < 8; ++jj) {
      float nv = (v[jj] - mu) * rstd * flng[j0 + jj] + flnb[j0 + jj];
      dot += nv * linw[j0 + jj];
    }
#pragma unroll
    for (int mk = 1; mk < 16; mk <<= 1) dot += __shfl_xor(dot, mk, 64);
    if ((tid & 15) == 0) {
      float cm = (colsumS[c] > 0.f) ? 1.0f : 0.0f;
      float xcv = dot * cm;
      out[257 + g * CCd + c] = xcv;
      xcs[c] = xcv; axcs[c] = fabsf(xcv); msk[c] = cm;
    }
  }
  __syncthreads();
  if (tid == 0) {
    float so = 0.f, sa = 0.f, sd = 0.f;
#pragma unroll
    for (int k = 0; k < CCd; ++k) { so += xcs[k]; sa += axcs[k]; sd += msk[k] + 1e-7f; }
    out[g] = so + bias[0];
    l1g[g] = sa / sd;
  }
}

// ---------------- combine: losses = 0.01*reg + 0.01*mean_g(l1g) ----------------
__global__ __launch_bounds__(256) void combine_kernel(const float* __restrict__ l1g, const float* __restrict__ wsreg,
                                                      float* __restrict__ outp) {
  const int tid = threadIdx.x;
  float s2 = l1g[tid];
#pragma unroll
  for (int mk = 1; mk < 64; mk <<= 1) s2 += __shfl_xor(s2, mk, 64);
  __shared__ float rs2[4];
  if ((tid & 63) == 0) rs2[tid >> 6] = s2;
  __syncthreads();
  if (tid == 0) {
    float l1 = (rs2[0] + rs2[1] + rs2[2] + rs2[3]) * (1.0f / GG);
    outp[0] = 0.01f * wsreg[0] + 0.01f * l1;
  }
}

extern "C" void kernel_launch(void* const* d_in, const int* in_sizes, int n_in,
                              void* d_out, int out_size, void* d_ws, size_t ws_size,
                              hipStream_t stream) {
  (void)in_sizes; (void)n_in; (void)out_size; (void)ws_size;
  const float* x    = (const float*)d_in[0];
  const int*   ei   = (const int*)d_in[1];
  const int*   mask = (const int*)d_in[2];
  const float* s    = (const float*)d_in[3];
  const float* Wn   = (const float*)d_in[5];
  const float* bn   = (const float*)d_in[6];
  const float* Wo   = (const float*)d_in[7];
  const float* bo   = (const float*)d_in[8];
  const float* Wr   = (const float*)d_in[9];
  const float* lng  = (const float*)d_in[10];
  const float* lnb  = (const float*)d_in[11];
  const float* flng = (const float*)d_in[12];
  const float* flnb = (const float*)d_in[13];
  const float* linw = (const float*)d_in[14];
  const float* bias = (const float*)d_in[15];
  float* out = (float*)d_out;

  char* ws = (char*)d_ws;
  size_t off = 0;
  auto alloc = [&](size_t b) { char* p = ws + off; off += (b + 255) & ~(size_t)255; return p; };
  unsigned short* Wnb = (unsigned short*)alloc((size_t)LLd * HD * HD * 2);
  unsigned short* Wob = (unsigned short*)alloc((size_t)LLd * HD * HD * 2);
  unsigned short* Wrb = (unsigned short*)alloc((size_t)LLd * HD * HD * 2);
  float* l1g    = (float*)alloc((size_t)GG * 4);
  float* wsreg  = (float*)alloc(256);

  const int* srcA = ei;
  const int* tgtA = ei + EE;

  hipMemsetAsync(wsreg, 0, 4, stream);
  convert_w_kernel<<<LLd * HD * HD / (256 * 4), 256, 0, stream>>>(Wn, Wo, Wr, bo,
      (unsigned*)Wnb, (unsigned*)Wob, (unsigned*)Wrb, wsreg);
  fused_kernel<<<GG, 512, 0, stream>>>(x, srcA, tgtA, mask, Wnb, Wob, Wrb, bn, bo,
                                       lng, lnb, s, flng, flnb, linw, bias, out, l1g);
  combine_kernel<<<1, 256, 0, stream>>>(l1g, wsreg, out + 256);
}